// Round 7
// baseline (529.506 us; speedup 1.0000x reference)
//
#include <hip/hip_runtime.h>

#define D 4096
#define RANK 1024
#define K2 2048
#define UELEMS 4194304ULL   // D*RANK
#define NTOT 16777216ULL    // 4^12 = D*D
#define QSCALE 16000.0f

typedef __attribute__((ext_vector_type(4))) int i32x4;

__device__ float g_inv_tr[1];
__device__ float g_scale[D];

static __device__ __forceinline__ void load_lds16(const void* g, void* l) {
    __builtin_amdgcn_global_load_lds(
        (const __attribute__((address_space(1))) unsigned int*)g,
        (__attribute__((address_space(3))) unsigned int*)l, 16, 0, 0);
}

// ---------------------------------------------------------------------------
// i8 split quantization of W = [Ur | Ui] with per-row scale (verified r6).
// ---------------------------------------------------------------------------
__global__ __launch_bounds__(256) void convert_w_i8(const float* __restrict__ P,
                                                    char* __restrict__ Wh,
                                                    char* __restrict__ Wl,
                                                    char* __restrict__ N2h,
                                                    char* __restrict__ N2l)
{
    const int w = threadIdx.x >> 6, lane = threadIdx.x & 63;
    const int row = blockIdx.x * 4 + w;

    float ur[16], ui[16];
    const float* pr = P + (size_t)row * RANK + lane * 16;
    const float* pi = P + UELEMS + (size_t)row * RANK + lane * 16;
    #pragma unroll
    for (int q = 0; q < 4; ++q) {
        const float4 a = ((const float4*)pr)[q];
        const float4 b = ((const float4*)pi)[q];
        ur[q * 4 + 0] = a.x; ur[q * 4 + 1] = a.y; ur[q * 4 + 2] = a.z; ur[q * 4 + 3] = a.w;
        ui[q * 4 + 0] = b.x; ui[q * 4 + 1] = b.y; ui[q * 4 + 2] = b.z; ui[q * 4 + 3] = b.w;
    }
    float mx = 0.f;
    #pragma unroll
    for (int e = 0; e < 16; ++e)
        mx = fmaxf(mx, fmaxf(fabsf(ur[e]), fabsf(ui[e])));
    #pragma unroll
    for (int off = 1; off < 64; off <<= 1)
        mx = fmaxf(mx, __shfl_xor(mx, off));
    const float inv = mx > 0.f ? QSCALE / mx : 0.f;
    if (lane == 0) g_scale[row] = mx / QSCALE;

    int hr[16], lr[16], hi[16], li[16];
    #pragma unroll
    for (int e = 0; e < 16; ++e) {
        float q = ur[e] * inv;
        float hf = rintf(q * 0.0078125f);
        hr[e] = (int)hf; lr[e] = (int)rintf(q - 128.f * hf);
        q = ui[e] * inv;
        hf = rintf(q * 0.0078125f);
        hi[e] = (int)hf; li[e] = (int)rintf(q - 128.f * hf);
    }
    uint4 phr, plr, phi, pli, pnh, pnl;
    unsigned* dst[6] = {(unsigned*)&phr, (unsigned*)&plr, (unsigned*)&phi,
                        (unsigned*)&pli, (unsigned*)&pnh, (unsigned*)&pnl};
    #pragma unroll
    for (int q = 0; q < 4; ++q) {
        unsigned a = 0, b = 0, c = 0, d = 0, e = 0, f = 0;
        #pragma unroll
        for (int k = 0; k < 4; ++k) {
            const int sh = k * 8;
            a |= (unsigned)(hr[q * 4 + k] & 255) << sh;
            b |= (unsigned)(lr[q * 4 + k] & 255) << sh;
            c |= (unsigned)(hi[q * 4 + k] & 255) << sh;
            d |= (unsigned)(li[q * 4 + k] & 255) << sh;
            e |= (unsigned)((-hi[q * 4 + k]) & 255) << sh;
            f |= (unsigned)((-li[q * 4 + k]) & 255) << sh;
        }
        dst[0][q] = a; dst[1][q] = b; dst[2][q] = c; dst[3][q] = d; dst[4][q] = e; dst[5][q] = f;
    }
    const size_t b1 = (size_t)row * 2048 + lane * 16;
    *(uint4*)&Wh[b1] = phr;          *(uint4*)&Wl[b1] = plr;
    *(uint4*)&Wh[b1 + 1024] = phi;   *(uint4*)&Wl[b1 + 1024] = pli;
    const size_t b2 = (size_t)row * 1024 + lane * 16;
    *(uint4*)&N2h[b2] = pnh;         *(uint4*)&N2l[b2] = pnl;
}

// ---------------------------------------------------------------------------
// Fused Hermitian GEMM in i8 (verified r6, unchanged).
// ---------------------------------------------------------------------------
__global__ __launch_bounds__(256, 2) void gemm_rho_i8(const char* __restrict__ Wh,
                                                      const char* __restrict__ Wl,
                                                      const char* __restrict__ N2h,
                                                      const char* __restrict__ N2l,
                                                      float2* __restrict__ rho)
{
    __shared__ __align__(16) char sA1h[64 * 64];
    __shared__ __align__(16) char sA1l[64 * 64];
    __shared__ __align__(16) char sA2h[64 * 64];
    __shared__ __align__(16) char sA2l[64 * 64];
    __shared__ __align__(16) char sB1h[128 * 64];
    __shared__ __align__(16) char sB1l[128 * 64];
    __shared__ __align__(16) char sB2h[128 * 64];
    __shared__ __align__(16) char sB2l[128 * 64];
    __shared__ __align__(16) char sN2h[128 * 64];
    __shared__ __align__(16) char sN2l[128 * 64];

    const int b = blockIdx.x;
    int bj = (int)((65.0f - sqrtf(4225.0f - 4.0f * (float)b)) * 0.5f);
    while (bj > 0 && bj * (65 - bj) > b) --bj;
    while ((bj + 1) * (64 - bj) <= b) ++bj;
    const int bi = 2 * bj + (b - bj * (65 - bj));
    const int row0 = bi << 6, col0 = bj << 7;
    const bool full = (bi >= 2 * bj + 2);

    const int t = threadIdx.x;
    const int lane = t & 63, w = t >> 6;
    const int wr = w >> 1, wc = w & 1;

    const int rowA = t >> 2;
    const int kcA = (t & 3) ^ ((rowA >> 1) & 3);
    const size_t aoff = (size_t)(row0 + rowA) * 2048 + kcA * 16;
    const int ldsA = t * 16;
    size_t boff[2], boffN[2]; int ldsB[2];
    #pragma unroll
    for (int q = 0; q < 2; ++q) {
        const int g = q * 256 + t;
        const int rowB = g >> 2;
        const int kcB = (g & 3) ^ ((rowB >> 1) & 3);
        boff[q]  = (size_t)(col0 + rowB) * 2048 + kcB * 16;
        boffN[q] = (size_t)(col0 + rowB) * 1024 + kcB * 16;
        ldsB[q] = g * 16;
    }

    const int m = lane & 15, gq = lane >> 4;
    const int fko = (gq ^ ((m >> 1) & 3)) * 16;

    i32x4 rehh[2][4], remx[2][4], imhh[2][4], immx[2][4];
    #pragma unroll
    for (int i = 0; i < 2; ++i)
        #pragma unroll
        for (int j = 0; j < 4; ++j) {
            rehh[i][j] = (i32x4){0, 0, 0, 0}; remx[i][j] = (i32x4){0, 0, 0, 0};
            imhh[i][j] = (i32x4){0, 0, 0, 0}; immx[i][j] = (i32x4){0, 0, 0, 0};
        }

    for (int kt = 0; kt < RANK; kt += 64) {
        load_lds16(Wh + aoff + kt,        &sA1h[ldsA]);
        load_lds16(Wl + aoff + kt,        &sA1l[ldsA]);
        load_lds16(Wh + aoff + kt + 1024, &sA2h[ldsA]);
        load_lds16(Wl + aoff + kt + 1024, &sA2l[ldsA]);
        #pragma unroll
        for (int q = 0; q < 2; ++q) {
            load_lds16(Wh + boff[q] + kt,        &sB1h[ldsB[q]]);
            load_lds16(Wl + boff[q] + kt,        &sB1l[ldsB[q]]);
            load_lds16(Wh + boff[q] + kt + 1024, &sB2h[ldsB[q]]);
            load_lds16(Wl + boff[q] + kt + 1024, &sB2l[ldsB[q]]);
            load_lds16(N2h + boffN[q] + kt,      &sN2h[ldsB[q]]);
            load_lds16(N2l + boffN[q] + kt,      &sN2l[ldsB[q]]);
        }
        __syncthreads();

        i32x4 fa1h[2], fa1l[2], fa2h[2], fa2l[2];
        #pragma unroll
        for (int i = 0; i < 2; ++i) {
            const int off = (wr * 32 + i * 16 + m) * 64 + fko;
            fa1h[i] = *(const i32x4*)&sA1h[off];
            fa1l[i] = *(const i32x4*)&sA1l[off];
            fa2h[i] = *(const i32x4*)&sA2h[off];
            fa2l[i] = *(const i32x4*)&sA2l[off];
        }
        #pragma unroll
        for (int j = 0; j < 4; ++j) {
            const int off = (wc * 64 + j * 16 + m) * 64 + fko;
            const i32x4 b1h = *(const i32x4*)&sB1h[off];
            const i32x4 b1l = *(const i32x4*)&sB1l[off];
            const i32x4 b2h = *(const i32x4*)&sB2h[off];
            const i32x4 b2l = *(const i32x4*)&sB2l[off];
            const i32x4 n2h = *(const i32x4*)&sN2h[off];
            const i32x4 n2l = *(const i32x4*)&sN2l[off];
            #pragma unroll
            for (int i = 0; i < 2; ++i) {
                i32x4 r = rehh[i][j];
                r = __builtin_amdgcn_mfma_i32_16x16x64_i8(fa1h[i], b1h, r, 0, 0, 0);
                r = __builtin_amdgcn_mfma_i32_16x16x64_i8(fa2h[i], b2h, r, 0, 0, 0);
                rehh[i][j] = r;
                r = remx[i][j];
                r = __builtin_amdgcn_mfma_i32_16x16x64_i8(fa1h[i], b1l, r, 0, 0, 0);
                r = __builtin_amdgcn_mfma_i32_16x16x64_i8(fa1l[i], b1h, r, 0, 0, 0);
                r = __builtin_amdgcn_mfma_i32_16x16x64_i8(fa2h[i], b2l, r, 0, 0, 0);
                r = __builtin_amdgcn_mfma_i32_16x16x64_i8(fa2l[i], b2h, r, 0, 0, 0);
                remx[i][j] = r;
                r = imhh[i][j];
                r = __builtin_amdgcn_mfma_i32_16x16x64_i8(fa2h[i], b1h, r, 0, 0, 0);
                r = __builtin_amdgcn_mfma_i32_16x16x64_i8(fa1h[i], n2h, r, 0, 0, 0);
                imhh[i][j] = r;
                r = immx[i][j];
                r = __builtin_amdgcn_mfma_i32_16x16x64_i8(fa2h[i], b1l, r, 0, 0, 0);
                r = __builtin_amdgcn_mfma_i32_16x16x64_i8(fa2l[i], b1h, r, 0, 0, 0);
                r = __builtin_amdgcn_mfma_i32_16x16x64_i8(fa1h[i], n2l, r, 0, 0, 0);
                r = __builtin_amdgcn_mfma_i32_16x16x64_i8(fa1l[i], n2h, r, 0, 0, 0);
                immx[i][j] = r;
            }
        }
        __syncthreads();
    }

    #pragma unroll
    for (int i = 0; i < 2; ++i)
        #pragma unroll
        for (int j = 0; j < 4; ++j) {
            const int col = col0 + wc * 64 + j * 16 + m;
            const float sc = g_scale[col];
            #pragma unroll
            for (int r = 0; r < 4; ++r) {
                const int row = row0 + wr * 32 + i * 16 + gq * 4 + r;
                const float s2 = g_scale[row] * sc;
                const float re = s2 * (16384.f * (float)rehh[i][j][r] + 128.f * (float)remx[i][j][r]);
                const float im = s2 * (16384.f * (float)imhh[i][j][r] + 128.f * (float)immx[i][j][r]);
                if (full || row >= col) rho[(size_t)row * D + col] = make_float2(re, im);
                if (full || row > col)  rho[(size_t)col * D + row] = make_float2(re, -im);
            }
        }
}

// ---------------------------------------------------------------------------
__global__ void trace_inv(const float2* __restrict__ rho)
{
    __shared__ float red[256];
    float s = 0.f;
    for (int d = threadIdx.x; d < D; d += 256)
        s += rho[(size_t)d * (D + 1)].x;
    red[threadIdx.x] = s;
    __syncthreads();
    for (int off = 128; off > 0; off >>= 1) {
        if (threadIdx.x < off) red[threadIdx.x] += red[threadIdx.x + off];
        __syncthreads();
    }
    if (threadIdx.x == 0) g_inv_tr[0] = 1.0f / red[0];
}

// ---------------------------------------------------------------------------
// Staged 3-qubit contraction, stages c and b in place (verified r4-r6).
// ---------------------------------------------------------------------------
static __device__ __forceinline__ void qmt_stage_cb(float2* x,
                                                    const float* __restrict__ Mre,
                                                    const float* __restrict__ Mim)
{
    #pragma unroll
    for (int jj = 0; jj < 4; ++jj) {
        float2 y[16];
        #pragma unroll
        for (int sc = 0; sc < 4; ++sc)
            #pragma unroll
            for (int ii = 0; ii < 4; ++ii) {
                float2 acc = make_float2(0.f, 0.f);
                #pragma unroll
                for (int ic = 0; ic < 2; ++ic)
                    #pragma unroll
                    for (int jc = 0; jc < 2; ++jc) {
                        const float mr = Mre[sc * 4 + ic * 2 + jc];
                        const float mi = Mim[sc * 4 + ic * 2 + jc];
                        const float2 v = x[jj * 16 + jc * 8 + ii * 2 + ic];
                        acc.x += mr * v.x - mi * v.y;
                        acc.y += mr * v.y + mi * v.x;
                    }
                y[sc * 4 + ii] = acc;
            }
        #pragma unroll
        for (int q = 0; q < 16; ++q) x[jj * 16 + q] = y[q];
    }

    #pragma unroll
    for (int ja = 0; ja < 2; ++ja)
        #pragma unroll
        for (int sc = 0; sc < 4; ++sc) {
            float2 z[8];
            #pragma unroll
            for (int sb = 0; sb < 4; ++sb)
                #pragma unroll
                for (int ia = 0; ia < 2; ++ia) {
                    float2 acc = make_float2(0.f, 0.f);
                    #pragma unroll
                    for (int ib = 0; ib < 2; ++ib)
                        #pragma unroll
                        for (int jb = 0; jb < 2; ++jb) {
                            const float mr = Mre[sb * 4 + ib * 2 + jb];
                            const float mi = Mim[sb * 4 + ib * 2 + jb];
                            const float2 v = x[(ja * 2 + jb) * 16 + sc * 4 + ia * 2 + ib];
                            acc.x += mr * v.x - mi * v.y;
                            acc.y += mr * v.y + mi * v.x;
                        }
                    z[sb * 2 + ia] = acc;
                }
            #pragma unroll
            for (int sb = 0; sb < 4; ++sb)
                #pragma unroll
                for (int ia = 0; ia < 2; ++ia)
                    x[ja * 32 + (sb >> 1) * 16 + sc * 4 + ia * 2 + (sb & 1)] = z[sb * 2 + ia];
        }
}

#define QMT_STAGE_A(STORE)                                                     \
    _Pragma("unroll")                                                          \
    for (int sbH = 0; sbH < 2; ++sbH)                                          \
        _Pragma("unroll")                                                      \
        for (int sc = 0; sc < 4; ++sc)                                         \
            _Pragma("unroll")                                                  \
            for (int sbL = 0; sbL < 2; ++sbL) {                                \
                const int sb = sbH * 2 + sbL;                                  \
                _Pragma("unroll")                                              \
                for (int sa = 0; sa < 4; ++sa) {                               \
                    float2 acc = make_float2(0.f, 0.f);                        \
                    _Pragma("unroll")                                          \
                    for (int ia = 0; ia < 2; ++ia)                             \
                        _Pragma("unroll")                                      \
                        for (int ja = 0; ja < 2; ++ja) {                       \
                            const float mr = Mre[sa * 4 + ia * 2 + ja];        \
                            const float mi = Mim[sa * 4 + ia * 2 + ja];        \
                            const float2 v = x[ja * 32 + sbH * 16 + sc * 4 + ia * 2 + sbL]; \
                            acc.x += mr * v.x - mi * v.y;                      \
                            acc.y += mr * v.y + mi * v.x;                      \
                        }                                                      \
                    const int s3 = sa * 16 + sb * 4 + sc;                      \
                    STORE;                                                     \
                }                                                              \
            }

// ---------------------------------------------------------------------------
// Fused pass A: contracts 6 LSB qubits (row/col bits 5..0) in one kernel.
// Group (rr,cc) = row/col bits 11..6; wave = 64 (a,t) slots (bits 5..3).
// Stage 1 contracts bits 2..0 (registers), 64x65-padded LDS transpose
// swaps ownership (a,t) <-> s3, stage 2 contracts bits 5..3.
// Output [rr, cc, s3'(64), s3(64)] — bit-identical to old p2's output.
// 4 waves share 66.5 KB LDS via two phases (4 uniform barriers).
// ---------------------------------------------------------------------------
__global__ __launch_bounds__(256, 2) void qmt_pA(const float2* __restrict__ in,
                                                 float2* __restrict__ out,
                                                 const float* __restrict__ Mre,
                                                 const float* __restrict__ Mim)
{
    __shared__ float2 xch[2][64 * 65];
    const int t = threadIdx.x;
    const int w = t >> 6, L = t & 63;
    const int grp = blockIdx.x * 4 + w;     // 4096 groups
    const int rr = grp >> 6, cc = grp & 63;
    const int a = L >> 3, tc = L & 7;

    float2 x[64];
    const size_t rb = ((size_t)(rr * 64 + a * 8)) * 4096 + cc * 64 + tc * 8;
    #pragma unroll
    for (int j3 = 0; j3 < 8; ++j3) {
        const float4* p = (const float4*)(in + rb + (size_t)j3 * 4096);
        #pragma unroll
        for (int q = 0; q < 4; ++q) {
            const float4 v = p[q];
            x[j3 * 8 + 2 * q]     = make_float2(v.x, v.y);
            x[j3 * 8 + 2 * q + 1] = make_float2(v.z, v.w);
        }
    }
    qmt_stage_cb(x, Mre, Mim);

    // two-phase LDS exchange: waves {0,1} then {2,3}
    #pragma unroll
    for (int ph = 0; ph < 2; ++ph) {
        __syncthreads();
        if ((w >> 1) == ph) {
            float2* X = xch[w & 1];
            QMT_STAGE_A(X[s3 * 65 + L] = acc)
        }
        __syncthreads();
        if ((w >> 1) == ph) {
            const float2* X = xch[w & 1];
            #pragma unroll
            for (int at = 0; at < 64; ++at) x[at] = X[L * 65 + at];
        }
    }

    qmt_stage_cb(x, Mre, Mim);
    const size_t ob = (size_t)grp * 4096 + L;
    QMT_STAGE_A(out[ob + s3 * 64] = acc)
}

// ---------------------------------------------------------------------------
// Pass B (= old p3): in [rr(64), cc(64), S(4096)]; out [r3,c3, s3(64), S].
// ---------------------------------------------------------------------------
__global__ __launch_bounds__(256) void qmt_p3(const float2* __restrict__ in,
                                              float2* __restrict__ out,
                                              const float* __restrict__ Mre,
                                              const float* __restrict__ Mim)
{
    const int tid = blockIdx.x * 256 + threadIdx.x;
    const int s = tid & 4095, c3 = (tid >> 12) & 7, r3 = tid >> 15;

    float2 x[64];
    #pragma unroll
    for (int j3 = 0; j3 < 8; ++j3)
        #pragma unroll
        for (int i3 = 0; i3 < 8; ++i3)
            x[j3 * 8 + i3] = in[(size_t)((r3 * 8 + j3) * 64 + c3 * 8 + i3) * 4096 + s];
    qmt_stage_cb(x, Mre, Mim);
    const size_t ob = ((size_t)(r3 * 8 + c3) * 64) * 4096 + s;
    QMT_STAGE_A(out[ob + s3 * 4096] = acc)
}

// ---------------------------------------------------------------------------
// Pass C (= old p4, MSB triplet): real-only out [s_hi, s3(64), s_lo(32)].
// ---------------------------------------------------------------------------
__global__ __launch_bounds__(256) void qmt_p4(const float2* __restrict__ in,
                                              float* __restrict__ out,
                                              const float* __restrict__ Mre,
                                              const float* __restrict__ Mim)
{
    const int tid = blockIdx.x * 256 + threadIdx.x;   // 2^18
    float2 x[64];
    #pragma unroll
    for (int j3 = 0; j3 < 8; ++j3)
        #pragma unroll
        for (int i3 = 0; i3 < 8; ++i3)
            x[j3 * 8 + i3] = in[(size_t)(j3 * 8 + i3) * 262144 + tid];
    qmt_stage_cb(x, Mre, Mim);
    const size_t ob = (size_t)(tid >> 5) * 2048 + (tid & 31);
    QMT_STAGE_A(out[ob + s3 * 32] = acc.x)
}

// ---------------------------------------------------------------------------
__global__ void gather_idx(const float* __restrict__ P, const int* __restrict__ idxs,
                           float* __restrict__ out, const int n)
{
    const int i = blockIdx.x * 256 + threadIdx.x;
    if (i < n) {
        const int idx = idxs[i];
        const int s = idx & 262143;
        const size_t pos = (size_t)(s >> 5) * 2048 + (size_t)(idx >> 18) * 32 + (s & 31);
        out[i] = P[pos] * g_inv_tr[0];
    }
}

// ---------------------------------------------------------------------------
extern "C" void kernel_launch(void* const* d_in, const int* in_sizes, int n_in,
                              void* d_out, int out_size, void* d_ws, size_t ws_size,
                              hipStream_t stream)
{
    const float* params = (const float*)d_in[0];  // (2, D, RANK) fp32
    const float* Mre    = (const float*)d_in[1];
    const float* Mim    = (const float*)d_in[2];
    const int*   idxs   = (const int*)d_in[3];
    float*       out    = (float*)d_out;

    float* ws = (float*)d_ws;
    float2* A  = (float2*)ws;                 // 134 MB plane
    float2* Bp = (float2*)(ws + 2 * NTOT);    // 134 MB plane
    // i8 planes in the (dead until pass A) B region: 25 MB
    char* Wh  = (char*)Bp;
    char* Wl  = Wh + (size_t)D * 2048;
    char* N2h = Wl + (size_t)D * 2048;
    char* N2l = N2h + (size_t)D * 1024;

    convert_w_i8<<<1024, 256, 0, stream>>>(params, Wh, Wl, N2h, N2l);
    gemm_rho_i8<<<1056, 256, 0, stream>>>(Wh, Wl, N2h, N2l, A);
    trace_inv<<<1, 256, 0, stream>>>(A);

    qmt_pA<<<1024, 256, 0, stream>>>(A, Bp, Mre, Mim);   // 6 qubits fused
    qmt_p3<<<1024, 256, 0, stream>>>(Bp, A, Mre, Mim);   // 3 qubits
    qmt_p4<<<1024, 256, 0, stream>>>(A, (float*)Bp, Mre, Mim);  // 3 qubits, real out

    gather_idx<<<(out_size + 255) / 256, 256, 0, stream>>>((float*)Bp, idxs, out, out_size);
}

// Round 8
// 517.221 us; speedup vs baseline: 1.0238x; 1.0238x over previous
//
#include <hip/hip_runtime.h>

#define D 4096
#define RANK 1024
#define K2 2048
#define UELEMS 4194304ULL   // D*RANK
#define NTOT 16777216ULL    // 4^12 = D*D
#define QSCALE 16000.0f

typedef __attribute__((ext_vector_type(4))) int i32x4;

__device__ float g_inv_tr[1];
__device__ float g_scale[D];

static __device__ __forceinline__ void load_lds16(const void* g, void* l) {
    __builtin_amdgcn_global_load_lds(
        (const __attribute__((address_space(1))) unsigned int*)g,
        (__attribute__((address_space(3))) unsigned int*)l, 16, 0, 0);
}

// ---------------------------------------------------------------------------
// i8 split quantization of W = [Ur | Ui] with per-row scale (verified r6).
// ---------------------------------------------------------------------------
__global__ __launch_bounds__(256) void convert_w_i8(const float* __restrict__ P,
                                                    char* __restrict__ Wh,
                                                    char* __restrict__ Wl,
                                                    char* __restrict__ N2h,
                                                    char* __restrict__ N2l)
{
    const int w = threadIdx.x >> 6, lane = threadIdx.x & 63;
    const int row = blockIdx.x * 4 + w;

    float ur[16], ui[16];
    const float* pr = P + (size_t)row * RANK + lane * 16;
    const float* pi = P + UELEMS + (size_t)row * RANK + lane * 16;
    #pragma unroll
    for (int q = 0; q < 4; ++q) {
        const float4 a = ((const float4*)pr)[q];
        const float4 b = ((const float4*)pi)[q];
        ur[q * 4 + 0] = a.x; ur[q * 4 + 1] = a.y; ur[q * 4 + 2] = a.z; ur[q * 4 + 3] = a.w;
        ui[q * 4 + 0] = b.x; ui[q * 4 + 1] = b.y; ui[q * 4 + 2] = b.z; ui[q * 4 + 3] = b.w;
    }
    float mx = 0.f;
    #pragma unroll
    for (int e = 0; e < 16; ++e)
        mx = fmaxf(mx, fmaxf(fabsf(ur[e]), fabsf(ui[e])));
    #pragma unroll
    for (int off = 1; off < 64; off <<= 1)
        mx = fmaxf(mx, __shfl_xor(mx, off));
    const float inv = mx > 0.f ? QSCALE / mx : 0.f;
    if (lane == 0) g_scale[row] = mx / QSCALE;

    int hr[16], lr[16], hi[16], li[16];
    #pragma unroll
    for (int e = 0; e < 16; ++e) {
        float q = ur[e] * inv;
        float hf = rintf(q * 0.0078125f);
        hr[e] = (int)hf; lr[e] = (int)rintf(q - 128.f * hf);
        q = ui[e] * inv;
        hf = rintf(q * 0.0078125f);
        hi[e] = (int)hf; li[e] = (int)rintf(q - 128.f * hf);
    }
    uint4 phr, plr, phi, pli, pnh, pnl;
    unsigned* dst[6] = {(unsigned*)&phr, (unsigned*)&plr, (unsigned*)&phi,
                        (unsigned*)&pli, (unsigned*)&pnh, (unsigned*)&pnl};
    #pragma unroll
    for (int q = 0; q < 4; ++q) {
        unsigned a = 0, b = 0, c = 0, d = 0, e = 0, f = 0;
        #pragma unroll
        for (int k = 0; k < 4; ++k) {
            const int sh = k * 8;
            a |= (unsigned)(hr[q * 4 + k] & 255) << sh;
            b |= (unsigned)(lr[q * 4 + k] & 255) << sh;
            c |= (unsigned)(hi[q * 4 + k] & 255) << sh;
            d |= (unsigned)(li[q * 4 + k] & 255) << sh;
            e |= (unsigned)((-hi[q * 4 + k]) & 255) << sh;
            f |= (unsigned)((-li[q * 4 + k]) & 255) << sh;
        }
        dst[0][q] = a; dst[1][q] = b; dst[2][q] = c; dst[3][q] = d; dst[4][q] = e; dst[5][q] = f;
    }
    const size_t b1 = (size_t)row * 2048 + lane * 16;
    *(uint4*)&Wh[b1] = phr;          *(uint4*)&Wl[b1] = plr;
    *(uint4*)&Wh[b1 + 1024] = phi;   *(uint4*)&Wl[b1 + 1024] = pli;
    const size_t b2 = (size_t)row * 1024 + lane * 16;
    *(uint4*)&N2h[b2] = pnh;         *(uint4*)&N2l[b2] = pnl;
}

// ---------------------------------------------------------------------------
// Fused Hermitian GEMM in i8 (verified r6, unchanged).
// ---------------------------------------------------------------------------
__global__ __launch_bounds__(256, 2) void gemm_rho_i8(const char* __restrict__ Wh,
                                                      const char* __restrict__ Wl,
                                                      const char* __restrict__ N2h,
                                                      const char* __restrict__ N2l,
                                                      float2* __restrict__ rho)
{
    __shared__ __align__(16) char sA1h[64 * 64];
    __shared__ __align__(16) char sA1l[64 * 64];
    __shared__ __align__(16) char sA2h[64 * 64];
    __shared__ __align__(16) char sA2l[64 * 64];
    __shared__ __align__(16) char sB1h[128 * 64];
    __shared__ __align__(16) char sB1l[128 * 64];
    __shared__ __align__(16) char sB2h[128 * 64];
    __shared__ __align__(16) char sB2l[128 * 64];
    __shared__ __align__(16) char sN2h[128 * 64];
    __shared__ __align__(16) char sN2l[128 * 64];

    const int b = blockIdx.x;
    int bj = (int)((65.0f - sqrtf(4225.0f - 4.0f * (float)b)) * 0.5f);
    while (bj > 0 && bj * (65 - bj) > b) --bj;
    while ((bj + 1) * (64 - bj) <= b) ++bj;
    const int bi = 2 * bj + (b - bj * (65 - bj));
    const int row0 = bi << 6, col0 = bj << 7;
    const bool full = (bi >= 2 * bj + 2);

    const int t = threadIdx.x;
    const int lane = t & 63, w = t >> 6;
    const int wr = w >> 1, wc = w & 1;

    const int rowA = t >> 2;
    const int kcA = (t & 3) ^ ((rowA >> 1) & 3);
    const size_t aoff = (size_t)(row0 + rowA) * 2048 + kcA * 16;
    const int ldsA = t * 16;
    size_t boff[2], boffN[2]; int ldsB[2];
    #pragma unroll
    for (int q = 0; q < 2; ++q) {
        const int g = q * 256 + t;
        const int rowB = g >> 2;
        const int kcB = (g & 3) ^ ((rowB >> 1) & 3);
        boff[q]  = (size_t)(col0 + rowB) * 2048 + kcB * 16;
        boffN[q] = (size_t)(col0 + rowB) * 1024 + kcB * 16;
        ldsB[q] = g * 16;
    }

    const int m = lane & 15, gq = lane >> 4;
    const int fko = (gq ^ ((m >> 1) & 3)) * 16;

    i32x4 rehh[2][4], remx[2][4], imhh[2][4], immx[2][4];
    #pragma unroll
    for (int i = 0; i < 2; ++i)
        #pragma unroll
        for (int j = 0; j < 4; ++j) {
            rehh[i][j] = (i32x4){0, 0, 0, 0}; remx[i][j] = (i32x4){0, 0, 0, 0};
            imhh[i][j] = (i32x4){0, 0, 0, 0}; immx[i][j] = (i32x4){0, 0, 0, 0};
        }

    for (int kt = 0; kt < RANK; kt += 64) {
        load_lds16(Wh + aoff + kt,        &sA1h[ldsA]);
        load_lds16(Wl + aoff + kt,        &sA1l[ldsA]);
        load_lds16(Wh + aoff + kt + 1024, &sA2h[ldsA]);
        load_lds16(Wl + aoff + kt + 1024, &sA2l[ldsA]);
        #pragma unroll
        for (int q = 0; q < 2; ++q) {
            load_lds16(Wh + boff[q] + kt,        &sB1h[ldsB[q]]);
            load_lds16(Wl + boff[q] + kt,        &sB1l[ldsB[q]]);
            load_lds16(Wh + boff[q] + kt + 1024, &sB2h[ldsB[q]]);
            load_lds16(Wl + boff[q] + kt + 1024, &sB2l[ldsB[q]]);
            load_lds16(N2h + boffN[q] + kt,      &sN2h[ldsB[q]]);
            load_lds16(N2l + boffN[q] + kt,      &sN2l[ldsB[q]]);
        }
        __syncthreads();

        i32x4 fa1h[2], fa1l[2], fa2h[2], fa2l[2];
        #pragma unroll
        for (int i = 0; i < 2; ++i) {
            const int off = (wr * 32 + i * 16 + m) * 64 + fko;
            fa1h[i] = *(const i32x4*)&sA1h[off];
            fa1l[i] = *(const i32x4*)&sA1l[off];
            fa2h[i] = *(const i32x4*)&sA2h[off];
            fa2l[i] = *(const i32x4*)&sA2l[off];
        }
        #pragma unroll
        for (int j = 0; j < 4; ++j) {
            const int off = (wc * 64 + j * 16 + m) * 64 + fko;
            const i32x4 b1h = *(const i32x4*)&sB1h[off];
            const i32x4 b1l = *(const i32x4*)&sB1l[off];
            const i32x4 b2h = *(const i32x4*)&sB2h[off];
            const i32x4 b2l = *(const i32x4*)&sB2l[off];
            const i32x4 n2h = *(const i32x4*)&sN2h[off];
            const i32x4 n2l = *(const i32x4*)&sN2l[off];
            #pragma unroll
            for (int i = 0; i < 2; ++i) {
                i32x4 r = rehh[i][j];
                r = __builtin_amdgcn_mfma_i32_16x16x64_i8(fa1h[i], b1h, r, 0, 0, 0);
                r = __builtin_amdgcn_mfma_i32_16x16x64_i8(fa2h[i], b2h, r, 0, 0, 0);
                rehh[i][j] = r;
                r = remx[i][j];
                r = __builtin_amdgcn_mfma_i32_16x16x64_i8(fa1h[i], b1l, r, 0, 0, 0);
                r = __builtin_amdgcn_mfma_i32_16x16x64_i8(fa1l[i], b1h, r, 0, 0, 0);
                r = __builtin_amdgcn_mfma_i32_16x16x64_i8(fa2h[i], b2l, r, 0, 0, 0);
                r = __builtin_amdgcn_mfma_i32_16x16x64_i8(fa2l[i], b2h, r, 0, 0, 0);
                remx[i][j] = r;
                r = imhh[i][j];
                r = __builtin_amdgcn_mfma_i32_16x16x64_i8(fa2h[i], b1h, r, 0, 0, 0);
                r = __builtin_amdgcn_mfma_i32_16x16x64_i8(fa1h[i], n2h, r, 0, 0, 0);
                imhh[i][j] = r;
                r = immx[i][j];
                r = __builtin_amdgcn_mfma_i32_16x16x64_i8(fa2h[i], b1l, r, 0, 0, 0);
                r = __builtin_amdgcn_mfma_i32_16x16x64_i8(fa2l[i], b1h, r, 0, 0, 0);
                r = __builtin_amdgcn_mfma_i32_16x16x64_i8(fa1h[i], n2l, r, 0, 0, 0);
                r = __builtin_amdgcn_mfma_i32_16x16x64_i8(fa1l[i], n2h, r, 0, 0, 0);
                immx[i][j] = r;
            }
        }
        __syncthreads();
    }

    #pragma unroll
    for (int i = 0; i < 2; ++i)
        #pragma unroll
        for (int j = 0; j < 4; ++j) {
            const int col = col0 + wc * 64 + j * 16 + m;
            const float sc = g_scale[col];
            #pragma unroll
            for (int r = 0; r < 4; ++r) {
                const int row = row0 + wr * 32 + i * 16 + gq * 4 + r;
                const float s2 = g_scale[row] * sc;
                const float re = s2 * (16384.f * (float)rehh[i][j][r] + 128.f * (float)remx[i][j][r]);
                const float im = s2 * (16384.f * (float)imhh[i][j][r] + 128.f * (float)immx[i][j][r]);
                if (full || row >= col) rho[(size_t)row * D + col] = make_float2(re, im);
                if (full || row > col)  rho[(size_t)col * D + row] = make_float2(re, -im);
            }
        }
}

// ---------------------------------------------------------------------------
__global__ void trace_inv(const float2* __restrict__ rho)
{
    __shared__ float red[256];
    float s = 0.f;
    for (int d = threadIdx.x; d < D; d += 256)
        s += rho[(size_t)d * (D + 1)].x;
    red[threadIdx.x] = s;
    __syncthreads();
    for (int off = 128; off > 0; off >>= 1) {
        if (threadIdx.x < off) red[threadIdx.x] += red[threadIdx.x + off];
        __syncthreads();
    }
    if (threadIdx.x == 0) g_inv_tr[0] = 1.0f / red[0];
}

// ---------------------------------------------------------------------------
// Staged 3-qubit contraction, stages c and b in place (verified r4-r7).
// ---------------------------------------------------------------------------
static __device__ __forceinline__ void qmt_stage_cb(float2* x,
                                                    const float* __restrict__ Mre,
                                                    const float* __restrict__ Mim)
{
    #pragma unroll
    for (int jj = 0; jj < 4; ++jj) {
        float2 y[16];
        #pragma unroll
        for (int sc = 0; sc < 4; ++sc)
            #pragma unroll
            for (int ii = 0; ii < 4; ++ii) {
                float2 acc = make_float2(0.f, 0.f);
                #pragma unroll
                for (int ic = 0; ic < 2; ++ic)
                    #pragma unroll
                    for (int jc = 0; jc < 2; ++jc) {
                        const float mr = Mre[sc * 4 + ic * 2 + jc];
                        const float mi = Mim[sc * 4 + ic * 2 + jc];
                        const float2 v = x[jj * 16 + jc * 8 + ii * 2 + ic];
                        acc.x += mr * v.x - mi * v.y;
                        acc.y += mr * v.y + mi * v.x;
                    }
                y[sc * 4 + ii] = acc;
            }
        #pragma unroll
        for (int q = 0; q < 16; ++q) x[jj * 16 + q] = y[q];
    }

    #pragma unroll
    for (int ja = 0; ja < 2; ++ja)
        #pragma unroll
        for (int sc = 0; sc < 4; ++sc) {
            float2 z[8];
            #pragma unroll
            for (int sb = 0; sb < 4; ++sb)
                #pragma unroll
                for (int ia = 0; ia < 2; ++ia) {
                    float2 acc = make_float2(0.f, 0.f);
                    #pragma unroll
                    for (int ib = 0; ib < 2; ++ib)
                        #pragma unroll
                        for (int jb = 0; jb < 2; ++jb) {
                            const float mr = Mre[sb * 4 + ib * 2 + jb];
                            const float mi = Mim[sb * 4 + ib * 2 + jb];
                            const float2 v = x[(ja * 2 + jb) * 16 + sc * 4 + ia * 2 + ib];
                            acc.x += mr * v.x - mi * v.y;
                            acc.y += mr * v.y + mi * v.x;
                        }
                    z[sb * 2 + ia] = acc;
                }
            #pragma unroll
            for (int sb = 0; sb < 4; ++sb)
                #pragma unroll
                for (int ia = 0; ia < 2; ++ia)
                    x[ja * 32 + (sb >> 1) * 16 + sc * 4 + ia * 2 + (sb & 1)] = z[sb * 2 + ia];
        }
}

#define QMT_STAGE_A(STORE)                                                     \
    _Pragma("unroll")                                                          \
    for (int sbH = 0; sbH < 2; ++sbH)                                          \
        _Pragma("unroll")                                                      \
        for (int sc = 0; sc < 4; ++sc)                                         \
            _Pragma("unroll")                                                  \
            for (int sbL = 0; sbL < 2; ++sbL) {                                \
                const int sb = sbH * 2 + sbL;                                  \
                _Pragma("unroll")                                              \
                for (int sa = 0; sa < 4; ++sa) {                               \
                    float2 acc = make_float2(0.f, 0.f);                        \
                    _Pragma("unroll")                                          \
                    for (int ia = 0; ia < 2; ++ia)                             \
                        _Pragma("unroll")                                      \
                        for (int ja = 0; ja < 2; ++ja) {                       \
                            const float mr = Mre[sa * 4 + ia * 2 + ja];        \
                            const float mi = Mim[sa * 4 + ia * 2 + ja];        \
                            const float2 v = x[ja * 32 + sbH * 16 + sc * 4 + ia * 2 + sbL]; \
                            acc.x += mr * v.x - mi * v.y;                      \
                            acc.y += mr * v.y + mi * v.x;                      \
                        }                                                      \
                    const int s3 = sa * 16 + sb * 4 + sc;                      \
                    STORE;                                                     \
                }                                                              \
            }

// ---------------------------------------------------------------------------
// Fused pass A (round-8 restructure): 6 LSB qubits, ONE WAVE PER BLOCK.
// 64 threads, private 64x66-padded LDS tile (33.8 KB -> 4 blocks/CU).
// x is fully consumed by the stage-a LDS writes and reloaded after the
// barrier -> nothing lives across it -> no spill (r7's phased version
// spilled ~90 MB to scratch and ran at 0.4% occupancy).
// Output [rr, cc, s3'(64), s3(64)] — identical to r6's p2 output.
// ---------------------------------------------------------------------------
__global__ __launch_bounds__(64) void qmt_pA(const float2* __restrict__ in,
                                             float2* __restrict__ out,
                                             const float* __restrict__ Mre,
                                             const float* __restrict__ Mim)
{
    __shared__ __align__(16) float2 X[64 * 66];
    const int L = threadIdx.x;
    const int grp = blockIdx.x;             // 4096 groups = (rr, cc)
    const int rr = grp >> 6, cc = grp & 63;
    const int a = L >> 3, tc = L & 7;

    float2 x[64];
    const size_t rb = ((size_t)(rr * 64 + a * 8)) * 4096 + cc * 64 + tc * 8;
    #pragma unroll
    for (int j3 = 0; j3 < 8; ++j3) {
        const float4* p = (const float4*)(in + rb + (size_t)j3 * 4096);
        #pragma unroll
        for (int q = 0; q < 4; ++q) {
            const float4 v = p[q];
            x[j3 * 8 + 2 * q]     = make_float2(v.x, v.y);
            x[j3 * 8 + 2 * q + 1] = make_float2(v.z, v.w);
        }
    }
    qmt_stage_cb(x, Mre, Mim);
    QMT_STAGE_A(X[s3 * 66 + L] = acc)
    __syncthreads();
    #pragma unroll
    for (int at = 0; at < 64; at += 2) {
        const float4 v = *(const float4*)&X[L * 66 + at];
        x[at]     = make_float2(v.x, v.y);
        x[at + 1] = make_float2(v.z, v.w);
    }
    qmt_stage_cb(x, Mre, Mim);
    const size_t ob = (size_t)grp * 4096 + L;
    QMT_STAGE_A(out[ob + s3 * 64] = acc)
}

// ---------------------------------------------------------------------------
// Pass B (= old p3): in [rr(64), cc(64), S(4096)]; out [r3,c3, s3(64), S].
// ---------------------------------------------------------------------------
__global__ __launch_bounds__(256) void qmt_p3(const float2* __restrict__ in,
                                              float2* __restrict__ out,
                                              const float* __restrict__ Mre,
                                              const float* __restrict__ Mim)
{
    const int tid = blockIdx.x * 256 + threadIdx.x;
    const int s = tid & 4095, c3 = (tid >> 12) & 7, r3 = tid >> 15;

    float2 x[64];
    #pragma unroll
    for (int j3 = 0; j3 < 8; ++j3)
        #pragma unroll
        for (int i3 = 0; i3 < 8; ++i3)
            x[j3 * 8 + i3] = in[(size_t)((r3 * 8 + j3) * 64 + c3 * 8 + i3) * 4096 + s];
    qmt_stage_cb(x, Mre, Mim);
    const size_t ob = ((size_t)(r3 * 8 + c3) * 64) * 4096 + s;
    QMT_STAGE_A(out[ob + s3 * 4096] = acc)
}

// ---------------------------------------------------------------------------
// Pass C (= old p4, MSB triplet): real-only out [s_hi, s3(64), s_lo(32)].
// ---------------------------------------------------------------------------
__global__ __launch_bounds__(256) void qmt_p4(const float2* __restrict__ in,
                                              float* __restrict__ out,
                                              const float* __restrict__ Mre,
                                              const float* __restrict__ Mim)
{
    const int tid = blockIdx.x * 256 + threadIdx.x;   // 2^18
    float2 x[64];
    #pragma unroll
    for (int j3 = 0; j3 < 8; ++j3)
        #pragma unroll
        for (int i3 = 0; i3 < 8; ++i3)
            x[j3 * 8 + i3] = in[(size_t)(j3 * 8 + i3) * 262144 + tid];
    qmt_stage_cb(x, Mre, Mim);
    const size_t ob = (size_t)(tid >> 5) * 2048 + (tid & 31);
    QMT_STAGE_A(out[ob + s3 * 32] = acc.x)
}

// ---------------------------------------------------------------------------
__global__ void gather_idx(const float* __restrict__ P, const int* __restrict__ idxs,
                           float* __restrict__ out, const int n)
{
    const int i = blockIdx.x * 256 + threadIdx.x;
    if (i < n) {
        const int idx = idxs[i];
        const int s = idx & 262143;
        const size_t pos = (size_t)(s >> 5) * 2048 + (size_t)(idx >> 18) * 32 + (s & 31);
        out[i] = P[pos] * g_inv_tr[0];
    }
}

// ---------------------------------------------------------------------------
extern "C" void kernel_launch(void* const* d_in, const int* in_sizes, int n_in,
                              void* d_out, int out_size, void* d_ws, size_t ws_size,
                              hipStream_t stream)
{
    const float* params = (const float*)d_in[0];  // (2, D, RANK) fp32
    const float* Mre    = (const float*)d_in[1];
    const float* Mim    = (const float*)d_in[2];
    const int*   idxs   = (const int*)d_in[3];
    float*       out    = (float*)d_out;

    float* ws = (float*)d_ws;
    float2* A  = (float2*)ws;                 // 134 MB plane
    float2* Bp = (float2*)(ws + 2 * NTOT);    // 134 MB plane
    // i8 planes in the (dead until pass A) B region: 25 MB
    char* Wh  = (char*)Bp;
    char* Wl  = Wh + (size_t)D * 2048;
    char* N2h = Wl + (size_t)D * 2048;
    char* N2l = N2h + (size_t)D * 1024;

    convert_w_i8<<<1024, 256, 0, stream>>>(params, Wh, Wl, N2h, N2l);
    gemm_rho_i8<<<1056, 256, 0, stream>>>(Wh, Wl, N2h, N2l, A);
    trace_inv<<<1, 256, 0, stream>>>(A);

    qmt_pA<<<4096, 64, 0, stream>>>(A, Bp, Mre, Mim);   // 6 qubits fused
    qmt_p3<<<1024, 256, 0, stream>>>(Bp, A, Mre, Mim);  // 3 qubits
    qmt_p4<<<1024, 256, 0, stream>>>(A, (float*)Bp, Mre, Mim);  // 3 qubits, real out

    gather_idx<<<(out_size + 255) / 256, 256, 0, stream>>>((float*)Bp, idxs, out, out_size);
}

// Round 9
// 449.550 us; speedup vs baseline: 1.1779x; 1.1505x over previous
//
#include <hip/hip_runtime.h>

#define D 4096
#define RANK 1024
#define K2 2048
#define UELEMS 4194304ULL   // D*RANK
#define NTOT 16777216ULL    // 4^12 = D*D
#define QSCALE 16000.0f

typedef __attribute__((ext_vector_type(4))) int i32x4;

__device__ float g_inv_tr[1];
__device__ float g_scale[D];

static __device__ __forceinline__ void load_lds16(const void* g, void* l) {
    __builtin_amdgcn_global_load_lds(
        (const __attribute__((address_space(1))) unsigned int*)g,
        (__attribute__((address_space(3))) unsigned int*)l, 16, 0, 0);
}

// ---------------------------------------------------------------------------
// i8 split quantization of W = [Ur | Ui] with per-row scale (verified r6).
// ---------------------------------------------------------------------------
__global__ __launch_bounds__(256) void convert_w_i8(const float* __restrict__ P,
                                                    char* __restrict__ Wh,
                                                    char* __restrict__ Wl,
                                                    char* __restrict__ N2h,
                                                    char* __restrict__ N2l)
{
    const int w = threadIdx.x >> 6, lane = threadIdx.x & 63;
    const int row = blockIdx.x * 4 + w;

    float ur[16], ui[16];
    const float* pr = P + (size_t)row * RANK + lane * 16;
    const float* pi = P + UELEMS + (size_t)row * RANK + lane * 16;
    #pragma unroll
    for (int q = 0; q < 4; ++q) {
        const float4 a = ((const float4*)pr)[q];
        const float4 b = ((const float4*)pi)[q];
        ur[q * 4 + 0] = a.x; ur[q * 4 + 1] = a.y; ur[q * 4 + 2] = a.z; ur[q * 4 + 3] = a.w;
        ui[q * 4 + 0] = b.x; ui[q * 4 + 1] = b.y; ui[q * 4 + 2] = b.z; ui[q * 4 + 3] = b.w;
    }
    float mx = 0.f;
    #pragma unroll
    for (int e = 0; e < 16; ++e)
        mx = fmaxf(mx, fmaxf(fabsf(ur[e]), fabsf(ui[e])));
    #pragma unroll
    for (int off = 1; off < 64; off <<= 1)
        mx = fmaxf(mx, __shfl_xor(mx, off));
    const float inv = mx > 0.f ? QSCALE / mx : 0.f;
    if (lane == 0) g_scale[row] = mx / QSCALE;

    int hr[16], lr[16], hi[16], li[16];
    #pragma unroll
    for (int e = 0; e < 16; ++e) {
        float q = ur[e] * inv;
        float hf = rintf(q * 0.0078125f);
        hr[e] = (int)hf; lr[e] = (int)rintf(q - 128.f * hf);
        q = ui[e] * inv;
        hf = rintf(q * 0.0078125f);
        hi[e] = (int)hf; li[e] = (int)rintf(q - 128.f * hf);
    }
    uint4 phr, plr, phi, pli, pnh, pnl;
    unsigned* dst[6] = {(unsigned*)&phr, (unsigned*)&plr, (unsigned*)&phi,
                        (unsigned*)&pli, (unsigned*)&pnh, (unsigned*)&pnl};
    #pragma unroll
    for (int q = 0; q < 4; ++q) {
        unsigned a = 0, b = 0, c = 0, d = 0, e = 0, f = 0;
        #pragma unroll
        for (int k = 0; k < 4; ++k) {
            const int sh = k * 8;
            a |= (unsigned)(hr[q * 4 + k] & 255) << sh;
            b |= (unsigned)(lr[q * 4 + k] & 255) << sh;
            c |= (unsigned)(hi[q * 4 + k] & 255) << sh;
            d |= (unsigned)(li[q * 4 + k] & 255) << sh;
            e |= (unsigned)((-hi[q * 4 + k]) & 255) << sh;
            f |= (unsigned)((-li[q * 4 + k]) & 255) << sh;
        }
        dst[0][q] = a; dst[1][q] = b; dst[2][q] = c; dst[3][q] = d; dst[4][q] = e; dst[5][q] = f;
    }
    const size_t b1 = (size_t)row * 2048 + lane * 16;
    *(uint4*)&Wh[b1] = phr;          *(uint4*)&Wl[b1] = plr;
    *(uint4*)&Wh[b1 + 1024] = phi;   *(uint4*)&Wl[b1 + 1024] = pli;
    const size_t b2 = (size_t)row * 1024 + lane * 16;
    *(uint4*)&N2h[b2] = pnh;         *(uint4*)&N2l[b2] = pnl;
}

// ---------------------------------------------------------------------------
// Fused Hermitian GEMM in i8 (verified r6, unchanged).
// ---------------------------------------------------------------------------
__global__ __launch_bounds__(256, 2) void gemm_rho_i8(const char* __restrict__ Wh,
                                                      const char* __restrict__ Wl,
                                                      const char* __restrict__ N2h,
                                                      const char* __restrict__ N2l,
                                                      float2* __restrict__ rho)
{
    __shared__ __align__(16) char sA1h[64 * 64];
    __shared__ __align__(16) char sA1l[64 * 64];
    __shared__ __align__(16) char sA2h[64 * 64];
    __shared__ __align__(16) char sA2l[64 * 64];
    __shared__ __align__(16) char sB1h[128 * 64];
    __shared__ __align__(16) char sB1l[128 * 64];
    __shared__ __align__(16) char sB2h[128 * 64];
    __shared__ __align__(16) char sB2l[128 * 64];
    __shared__ __align__(16) char sN2h[128 * 64];
    __shared__ __align__(16) char sN2l[128 * 64];

    const int b = blockIdx.x;
    int bj = (int)((65.0f - sqrtf(4225.0f - 4.0f * (float)b)) * 0.5f);
    while (bj > 0 && bj * (65 - bj) > b) --bj;
    while ((bj + 1) * (64 - bj) <= b) ++bj;
    const int bi = 2 * bj + (b - bj * (65 - bj));
    const int row0 = bi << 6, col0 = bj << 7;
    const bool full = (bi >= 2 * bj + 2);

    const int t = threadIdx.x;
    const int lane = t & 63, w = t >> 6;
    const int wr = w >> 1, wc = w & 1;

    const int rowA = t >> 2;
    const int kcA = (t & 3) ^ ((rowA >> 1) & 3);
    const size_t aoff = (size_t)(row0 + rowA) * 2048 + kcA * 16;
    const int ldsA = t * 16;
    size_t boff[2], boffN[2]; int ldsB[2];
    #pragma unroll
    for (int q = 0; q < 2; ++q) {
        const int g = q * 256 + t;
        const int rowB = g >> 2;
        const int kcB = (g & 3) ^ ((rowB >> 1) & 3);
        boff[q]  = (size_t)(col0 + rowB) * 2048 + kcB * 16;
        boffN[q] = (size_t)(col0 + rowB) * 1024 + kcB * 16;
        ldsB[q] = g * 16;
    }

    const int m = lane & 15, gq = lane >> 4;
    const int fko = (gq ^ ((m >> 1) & 3)) * 16;

    i32x4 rehh[2][4], remx[2][4], imhh[2][4], immx[2][4];
    #pragma unroll
    for (int i = 0; i < 2; ++i)
        #pragma unroll
        for (int j = 0; j < 4; ++j) {
            rehh[i][j] = (i32x4){0, 0, 0, 0}; remx[i][j] = (i32x4){0, 0, 0, 0};
            imhh[i][j] = (i32x4){0, 0, 0, 0}; immx[i][j] = (i32x4){0, 0, 0, 0};
        }

    for (int kt = 0; kt < RANK; kt += 64) {
        load_lds16(Wh + aoff + kt,        &sA1h[ldsA]);
        load_lds16(Wl + aoff + kt,        &sA1l[ldsA]);
        load_lds16(Wh + aoff + kt + 1024, &sA2h[ldsA]);
        load_lds16(Wl + aoff + kt + 1024, &sA2l[ldsA]);
        #pragma unroll
        for (int q = 0; q < 2; ++q) {
            load_lds16(Wh + boff[q] + kt,        &sB1h[ldsB[q]]);
            load_lds16(Wl + boff[q] + kt,        &sB1l[ldsB[q]]);
            load_lds16(Wh + boff[q] + kt + 1024, &sB2h[ldsB[q]]);
            load_lds16(Wl + boff[q] + kt + 1024, &sB2l[ldsB[q]]);
            load_lds16(N2h + boffN[q] + kt,      &sN2h[ldsB[q]]);
            load_lds16(N2l + boffN[q] + kt,      &sN2l[ldsB[q]]);
        }
        __syncthreads();

        i32x4 fa1h[2], fa1l[2], fa2h[2], fa2l[2];
        #pragma unroll
        for (int i = 0; i < 2; ++i) {
            const int off = (wr * 32 + i * 16 + m) * 64 + fko;
            fa1h[i] = *(const i32x4*)&sA1h[off];
            fa1l[i] = *(const i32x4*)&sA1l[off];
            fa2h[i] = *(const i32x4*)&sA2h[off];
            fa2l[i] = *(const i32x4*)&sA2l[off];
        }
        #pragma unroll
        for (int j = 0; j < 4; ++j) {
            const int off = (wc * 64 + j * 16 + m) * 64 + fko;
            const i32x4 b1h = *(const i32x4*)&sB1h[off];
            const i32x4 b1l = *(const i32x4*)&sB1l[off];
            const i32x4 b2h = *(const i32x4*)&sB2h[off];
            const i32x4 b2l = *(const i32x4*)&sB2l[off];
            const i32x4 n2h = *(const i32x4*)&sN2h[off];
            const i32x4 n2l = *(const i32x4*)&sN2l[off];
            #pragma unroll
            for (int i = 0; i < 2; ++i) {
                i32x4 r = rehh[i][j];
                r = __builtin_amdgcn_mfma_i32_16x16x64_i8(fa1h[i], b1h, r, 0, 0, 0);
                r = __builtin_amdgcn_mfma_i32_16x16x64_i8(fa2h[i], b2h, r, 0, 0, 0);
                rehh[i][j] = r;
                r = remx[i][j];
                r = __builtin_amdgcn_mfma_i32_16x16x64_i8(fa1h[i], b1l, r, 0, 0, 0);
                r = __builtin_amdgcn_mfma_i32_16x16x64_i8(fa1l[i], b1h, r, 0, 0, 0);
                r = __builtin_amdgcn_mfma_i32_16x16x64_i8(fa2h[i], b2l, r, 0, 0, 0);
                r = __builtin_amdgcn_mfma_i32_16x16x64_i8(fa2l[i], b2h, r, 0, 0, 0);
                remx[i][j] = r;
                r = imhh[i][j];
                r = __builtin_amdgcn_mfma_i32_16x16x64_i8(fa2h[i], b1h, r, 0, 0, 0);
                r = __builtin_amdgcn_mfma_i32_16x16x64_i8(fa1h[i], n2h, r, 0, 0, 0);
                imhh[i][j] = r;
                r = immx[i][j];
                r = __builtin_amdgcn_mfma_i32_16x16x64_i8(fa2h[i], b1l, r, 0, 0, 0);
                r = __builtin_amdgcn_mfma_i32_16x16x64_i8(fa2l[i], b1h, r, 0, 0, 0);
                r = __builtin_amdgcn_mfma_i32_16x16x64_i8(fa1h[i], n2l, r, 0, 0, 0);
                r = __builtin_amdgcn_mfma_i32_16x16x64_i8(fa1l[i], n2h, r, 0, 0, 0);
                immx[i][j] = r;
            }
        }
        __syncthreads();
    }

    #pragma unroll
    for (int i = 0; i < 2; ++i)
        #pragma unroll
        for (int j = 0; j < 4; ++j) {
            const int col = col0 + wc * 64 + j * 16 + m;
            const float sc = g_scale[col];
            #pragma unroll
            for (int r = 0; r < 4; ++r) {
                const int row = row0 + wr * 32 + i * 16 + gq * 4 + r;
                const float s2 = g_scale[row] * sc;
                const float re = s2 * (16384.f * (float)rehh[i][j][r] + 128.f * (float)remx[i][j][r]);
                const float im = s2 * (16384.f * (float)imhh[i][j][r] + 128.f * (float)immx[i][j][r]);
                if (full || row >= col) rho[(size_t)row * D + col] = make_float2(re, im);
                if (full || row > col)  rho[(size_t)col * D + row] = make_float2(re, -im);
            }
        }
}

// ---------------------------------------------------------------------------
__global__ void trace_inv(const float2* __restrict__ rho)
{
    __shared__ float red[256];
    float s = 0.f;
    for (int d = threadIdx.x; d < D; d += 256)
        s += rho[(size_t)d * (D + 1)].x;
    red[threadIdx.x] = s;
    __syncthreads();
    for (int off = 128; off > 0; off >>= 1) {
        if (threadIdx.x < off) red[threadIdx.x] += red[threadIdx.x + off];
        __syncthreads();
    }
    if (threadIdx.x == 0) g_inv_tr[0] = 1.0f / red[0];
}

// ---------------------------------------------------------------------------
// 2-qubit staged contraction on a 4x4 (row-bits x col-bits) register tile.
// x[j*4+i], j = (j_a j_b) row bits (a = more significant), i = (i_a i_b).
// Result in place: x[s_a*4 + s_b].  128 cmul.
// ---------------------------------------------------------------------------
static __device__ __forceinline__ void qmt2(float2* x,
                                            const float* __restrict__ Mre,
                                            const float* __restrict__ Mim)
{
    float2 y[16];
    #pragma unroll
    for (int sb = 0; sb < 4; ++sb)
        #pragma unroll
        for (int ja = 0; ja < 2; ++ja)
            #pragma unroll
            for (int ia = 0; ia < 2; ++ia) {
                float2 acc = make_float2(0.f, 0.f);
                #pragma unroll
                for (int ib = 0; ib < 2; ++ib)
                    #pragma unroll
                    for (int jb = 0; jb < 2; ++jb) {
                        const float mr = Mre[sb * 4 + ib * 2 + jb];
                        const float mi = Mim[sb * 4 + ib * 2 + jb];
                        const float2 v = x[(ja * 2 + jb) * 4 + ia * 2 + ib];
                        acc.x += mr * v.x - mi * v.y;
                        acc.y += mr * v.y + mi * v.x;
                    }
                y[sb * 4 + ja * 2 + ia] = acc;
            }
    #pragma unroll
    for (int sa = 0; sa < 4; ++sa)
        #pragma unroll
        for (int sb = 0; sb < 4; ++sb) {
            float2 acc = make_float2(0.f, 0.f);
            #pragma unroll
            for (int ia = 0; ia < 2; ++ia)
                #pragma unroll
                for (int ja = 0; ja < 2; ++ja) {
                    const float mr = Mre[sa * 4 + ia * 2 + ja];
                    const float mi = Mim[sa * 4 + ia * 2 + ja];
                    const float2 v = y[sb * 4 + ja * 2 + ia];
                    acc.x += mr * v.x - mi * v.y;
                    acc.y += mr * v.y + mi * v.x;
                }
            x[sa * 4 + sb] = acc;
        }
}

// ---------------------------------------------------------------------------
// Fused pass A (r9): 6 LSB qubits, 256-thread blocks, 16 elems/thread,
// three 2-qubit stages with two padded-LDS ownership exchanges.
// group = (rr, cc) = row/col bits 11..6.  Stage 1: thread (a4,t4) owns
// row bits 1..0 x col bits 1..0 -> d1.  Exchange X1[(a4*16+t4)*17 + d1].
// Stage 2: thread (a2,t2,d1) contracts bits 3..2 -> d2.  Exchange
// X2[(a2*4+t2)*257 + d2*16 + d1].  Stage 3: thread (d2,d1) contracts
// bits 5..4 -> d3.  Output [rr, cc, d3 d2 d1] — identical to r8 pA.
// LDS 34.8 KB shared/reused -> 4 blocks/CU = 16 waves/CU (vs r8's 4).
// ---------------------------------------------------------------------------
__global__ __launch_bounds__(256) void qmt_pA(const float2* __restrict__ in,
                                              float2* __restrict__ out,
                                              const float* __restrict__ Mre,
                                              const float* __restrict__ Mim)
{
    __shared__ __align__(16) float2 X[256 * 17];   // 34816 B, reused for X2
    const int t = threadIdx.x;
    const int grp = blockIdx.x;             // 4096 groups = (rr, cc)
    const int rr = grp >> 6, cc = grp & 63;

    // ---- stage 1: qubits 11,12 (row/col bits 1..0)
    const int a4 = t >> 4, t4 = t & 15;
    float2 x[16];
    #pragma unroll
    for (int j2 = 0; j2 < 4; ++j2) {
        const float2* p = in + ((size_t)(rr * 64 + a4 * 4 + j2)) * 4096 + cc * 64 + t4 * 4;
        const float4 v0 = ((const float4*)p)[0];
        const float4 v1 = ((const float4*)p)[1];
        x[j2 * 4 + 0] = make_float2(v0.x, v0.y);
        x[j2 * 4 + 1] = make_float2(v0.z, v0.w);
        x[j2 * 4 + 2] = make_float2(v1.x, v1.y);
        x[j2 * 4 + 3] = make_float2(v1.z, v1.w);
    }
    qmt2(x, Mre, Mim);                       // x[d1]
    #pragma unroll
    for (int d = 0; d < 16; ++d) X[t * 17 + d] = x[d];
    __syncthreads();

    // ---- stage 2: qubits 9,10 (row/col bits 3..2)
    const int a2 = t >> 6, t2 = (t >> 4) & 3, d1 = t & 15;
    #pragma unroll
    for (int j2 = 0; j2 < 4; ++j2)
        #pragma unroll
        for (int i2 = 0; i2 < 4; ++i2)
            x[j2 * 4 + i2] = X[((a2 * 4 + j2) * 16 + t2 * 4 + i2) * 17 + d1];
    __syncthreads();                          // all X1 reads done before overwrite
    qmt2(x, Mre, Mim);                        // x[d2]
    #pragma unroll
    for (int d = 0; d < 16; ++d) X[(a2 * 4 + t2) * 257 + d * 16 + d1] = x[d];
    __syncthreads();

    // ---- stage 3: qubits 7,8 (row/col bits 5..4)
    const int e2 = t >> 4, e1 = t & 15;       // (d2, d1)
    #pragma unroll
    for (int j2 = 0; j2 < 4; ++j2)
        #pragma unroll
        for (int i2 = 0; i2 < 4; ++i2)
            x[j2 * 4 + i2] = X[(j2 * 4 + i2) * 257 + e2 * 16 + e1];
    qmt2(x, Mre, Mim);                        // x[d3]
    const size_t ob = (size_t)grp * 4096 + e2 * 16 + e1;
    #pragma unroll
    for (int d = 0; d < 16; ++d) out[ob + (size_t)d * 256] = x[d];
}

// ---------------------------------------------------------------------------
// Staged 3-qubit contraction, stages c and b in place (verified r4-r8) —
// still used by p3/p4.
// ---------------------------------------------------------------------------
static __device__ __forceinline__ void qmt_stage_cb(float2* x,
                                                    const float* __restrict__ Mre,
                                                    const float* __restrict__ Mim)
{
    #pragma unroll
    for (int jj = 0; jj < 4; ++jj) {
        float2 y[16];
        #pragma unroll
        for (int sc = 0; sc < 4; ++sc)
            #pragma unroll
            for (int ii = 0; ii < 4; ++ii) {
                float2 acc = make_float2(0.f, 0.f);
                #pragma unroll
                for (int ic = 0; ic < 2; ++ic)
                    #pragma unroll
                    for (int jc = 0; jc < 2; ++jc) {
                        const float mr = Mre[sc * 4 + ic * 2 + jc];
                        const float mi = Mim[sc * 4 + ic * 2 + jc];
                        const float2 v = x[jj * 16 + jc * 8 + ii * 2 + ic];
                        acc.x += mr * v.x - mi * v.y;
                        acc.y += mr * v.y + mi * v.x;
                    }
                y[sc * 4 + ii] = acc;
            }
        #pragma unroll
        for (int q = 0; q < 16; ++q) x[jj * 16 + q] = y[q];
    }

    #pragma unroll
    for (int ja = 0; ja < 2; ++ja)
        #pragma unroll
        for (int sc = 0; sc < 4; ++sc) {
            float2 z[8];
            #pragma unroll
            for (int sb = 0; sb < 4; ++sb)
                #pragma unroll
                for (int ia = 0; ia < 2; ++ia) {
                    float2 acc = make_float2(0.f, 0.f);
                    #pragma unroll
                    for (int ib = 0; ib < 2; ++ib)
                        #pragma unroll
                        for (int jb = 0; jb < 2; ++jb) {
                            const float mr = Mre[sb * 4 + ib * 2 + jb];
                            const float mi = Mim[sb * 4 + ib * 2 + jb];
                            const float2 v = x[(ja * 2 + jb) * 16 + sc * 4 + ia * 2 + ib];
                            acc.x += mr * v.x - mi * v.y;
                            acc.y += mr * v.y + mi * v.x;
                        }
                    z[sb * 2 + ia] = acc;
                }
            #pragma unroll
            for (int sb = 0; sb < 4; ++sb)
                #pragma unroll
                for (int ia = 0; ia < 2; ++ia)
                    x[ja * 32 + (sb >> 1) * 16 + sc * 4 + ia * 2 + (sb & 1)] = z[sb * 2 + ia];
        }
}

#define QMT_STAGE_A(STORE)                                                     \
    _Pragma("unroll")                                                          \
    for (int sbH = 0; sbH < 2; ++sbH)                                          \
        _Pragma("unroll")                                                      \
        for (int sc = 0; sc < 4; ++sc)                                         \
            _Pragma("unroll")                                                  \
            for (int sbL = 0; sbL < 2; ++sbL) {                                \
                const int sb = sbH * 2 + sbL;                                  \
                _Pragma("unroll")                                              \
                for (int sa = 0; sa < 4; ++sa) {                               \
                    float2 acc = make_float2(0.f, 0.f);                        \
                    _Pragma("unroll")                                          \
                    for (int ia = 0; ia < 2; ++ia)                             \
                        _Pragma("unroll")                                      \
                        for (int ja = 0; ja < 2; ++ja) {                       \
                            const float mr = Mre[sa * 4 + ia * 2 + ja];        \
                            const float mi = Mim[sa * 4 + ia * 2 + ja];        \
                            const float2 v = x[ja * 32 + sbH * 16 + sc * 4 + ia * 2 + sbL]; \
                            acc.x += mr * v.x - mi * v.y;                      \
                            acc.y += mr * v.y + mi * v.x;                      \
                        }                                                      \
                    const int s3 = sa * 16 + sb * 4 + sc;                      \
                    STORE;                                                     \
                }                                                              \
            }

// ---------------------------------------------------------------------------
// Pass B (= p3): in [rr(64), cc(64), S(4096)]; out [r3,c3, s3(64), S].
// ---------------------------------------------------------------------------
__global__ __launch_bounds__(256) void qmt_p3(const float2* __restrict__ in,
                                              float2* __restrict__ out,
                                              const float* __restrict__ Mre,
                                              const float* __restrict__ Mim)
{
    const int tid = blockIdx.x * 256 + threadIdx.x;
    const int s = tid & 4095, c3 = (tid >> 12) & 7, r3 = tid >> 15;

    float2 x[64];
    #pragma unroll
    for (int j3 = 0; j3 < 8; ++j3)
        #pragma unroll
        for (int i3 = 0; i3 < 8; ++i3)
            x[j3 * 8 + i3] = in[(size_t)((r3 * 8 + j3) * 64 + c3 * 8 + i3) * 4096 + s];
    qmt_stage_cb(x, Mre, Mim);
    const size_t ob = ((size_t)(r3 * 8 + c3) * 64) * 4096 + s;
    QMT_STAGE_A(out[ob + s3 * 4096] = acc)
}

// ---------------------------------------------------------------------------
// Pass C (= p4, MSB triplet): real-only out [s_hi, s3(64), s_lo(32)].
// ---------------------------------------------------------------------------
__global__ __launch_bounds__(256) void qmt_p4(const float2* __restrict__ in,
                                              float* __restrict__ out,
                                              const float* __restrict__ Mre,
                                              const float* __restrict__ Mim)
{
    const int tid = blockIdx.x * 256 + threadIdx.x;   // 2^18
    float2 x[64];
    #pragma unroll
    for (int j3 = 0; j3 < 8; ++j3)
        #pragma unroll
        for (int i3 = 0; i3 < 8; ++i3)
            x[j3 * 8 + i3] = in[(size_t)(j3 * 8 + i3) * 262144 + tid];
    qmt_stage_cb(x, Mre, Mim);
    const size_t ob = (size_t)(tid >> 5) * 2048 + (tid & 31);
    QMT_STAGE_A(out[ob + s3 * 32] = acc.x)
}

// ---------------------------------------------------------------------------
__global__ void gather_idx(const float* __restrict__ P, const int* __restrict__ idxs,
                           float* __restrict__ out, const int n)
{
    const int i = blockIdx.x * 256 + threadIdx.x;
    if (i < n) {
        const int idx = idxs[i];
        const int s = idx & 262143;
        const size_t pos = (size_t)(s >> 5) * 2048 + (size_t)(idx >> 18) * 32 + (s & 31);
        out[i] = P[pos] * g_inv_tr[0];
    }
}

// ---------------------------------------------------------------------------
extern "C" void kernel_launch(void* const* d_in, const int* in_sizes, int n_in,
                              void* d_out, int out_size, void* d_ws, size_t ws_size,
                              hipStream_t stream)
{
    const float* params = (const float*)d_in[0];  // (2, D, RANK) fp32
    const float* Mre    = (const float*)d_in[1];
    const float* Mim    = (const float*)d_in[2];
    const int*   idxs   = (const int*)d_in[3];
    float*       out    = (float*)d_out;

    float* ws = (float*)d_ws;
    float2* A  = (float2*)ws;                 // 134 MB plane
    float2* Bp = (float2*)(ws + 2 * NTOT);    // 134 MB plane
    // i8 planes in the (dead until pass A) B region: 25 MB
    char* Wh  = (char*)Bp;
    char* Wl  = Wh + (size_t)D * 2048;
    char* N2h = Wl + (size_t)D * 2048;
    char* N2l = N2h + (size_t)D * 1024;

    convert_w_i8<<<1024, 256, 0, stream>>>(params, Wh, Wl, N2h, N2l);
    gemm_rho_i8<<<1056, 256, 0, stream>>>(Wh, Wl, N2h, N2l, A);
    trace_inv<<<1, 256, 0, stream>>>(A);

    qmt_pA<<<4096, 256, 0, stream>>>(A, Bp, Mre, Mim);  // 6 LSB qubits fused
    qmt_p3<<<1024, 256, 0, stream>>>(Bp, A, Mre, Mim);  // 3 qubits
    qmt_p4<<<1024, 256, 0, stream>>>(A, (float*)Bp, Mre, Mim);  // 3 qubits, real out

    gather_idx<<<(out_size + 255) / 256, 256, 0, stream>>>((float*)Bp, idxs, out, out_size);
}

// Round 10
// 433.694 us; speedup vs baseline: 1.2209x; 1.0366x over previous
//
#include <hip/hip_runtime.h>

#define D 4096
#define RANK 1024
#define K2 2048
#define UELEMS 4194304ULL   // D*RANK
#define NTOT 16777216ULL    // 4^12 = D*D
#define QSCALE 16000.0f

typedef __attribute__((ext_vector_type(4))) int i32x4;

__device__ float g_inv_tr[1];
__device__ float g_scale[D];
__device__ float g_mdre[16];   // M-dagger tables: M†[s][i][j] = conj(M[s][j][i])
__device__ float g_mdim[16];

static __device__ __forceinline__ void load_lds16(const void* g, void* l) {
    __builtin_amdgcn_global_load_lds(
        (const __attribute__((address_space(1))) unsigned int*)g,
        (__attribute__((address_space(3))) unsigned int*)l, 16, 0, 0);
}

// ---------------------------------------------------------------------------
// i8 split quantization of W = [Ur | Ui] with per-row scale (verified r6).
// Also builds the M-dagger tables used by pA's mirror pass.
// ---------------------------------------------------------------------------
__global__ __launch_bounds__(256) void convert_w_i8(const float* __restrict__ P,
                                                    const float* __restrict__ Mre,
                                                    const float* __restrict__ Mim,
                                                    char* __restrict__ Wh,
                                                    char* __restrict__ Wl,
                                                    char* __restrict__ N2h,
                                                    char* __restrict__ N2l)
{
    if (blockIdx.x == 0 && threadIdx.x < 16) {
        const int s = threadIdx.x >> 2, i = (threadIdx.x >> 1) & 1, j = threadIdx.x & 1;
        g_mdre[threadIdx.x] =  Mre[s * 4 + j * 2 + i];
        g_mdim[threadIdx.x] = -Mim[s * 4 + j * 2 + i];
    }

    const int w = threadIdx.x >> 6, lane = threadIdx.x & 63;
    const int row = blockIdx.x * 4 + w;

    float ur[16], ui[16];
    const float* pr = P + (size_t)row * RANK + lane * 16;
    const float* pi = P + UELEMS + (size_t)row * RANK + lane * 16;
    #pragma unroll
    for (int q = 0; q < 4; ++q) {
        const float4 a = ((const float4*)pr)[q];
        const float4 b = ((const float4*)pi)[q];
        ur[q * 4 + 0] = a.x; ur[q * 4 + 1] = a.y; ur[q * 4 + 2] = a.z; ur[q * 4 + 3] = a.w;
        ui[q * 4 + 0] = b.x; ui[q * 4 + 1] = b.y; ui[q * 4 + 2] = b.z; ui[q * 4 + 3] = b.w;
    }
    float mx = 0.f;
    #pragma unroll
    for (int e = 0; e < 16; ++e)
        mx = fmaxf(mx, fmaxf(fabsf(ur[e]), fabsf(ui[e])));
    #pragma unroll
    for (int off = 1; off < 64; off <<= 1)
        mx = fmaxf(mx, __shfl_xor(mx, off));
    const float inv = mx > 0.f ? QSCALE / mx : 0.f;
    if (lane == 0) g_scale[row] = mx / QSCALE;

    int hr[16], lr[16], hi[16], li[16];
    #pragma unroll
    for (int e = 0; e < 16; ++e) {
        float q = ur[e] * inv;
        float hf = rintf(q * 0.0078125f);
        hr[e] = (int)hf; lr[e] = (int)rintf(q - 128.f * hf);
        q = ui[e] * inv;
        hf = rintf(q * 0.0078125f);
        hi[e] = (int)hf; li[e] = (int)rintf(q - 128.f * hf);
    }
    uint4 phr, plr, phi, pli, pnh, pnl;
    unsigned* dst[6] = {(unsigned*)&phr, (unsigned*)&plr, (unsigned*)&phi,
                        (unsigned*)&pli, (unsigned*)&pnh, (unsigned*)&pnl};
    #pragma unroll
    for (int q = 0; q < 4; ++q) {
        unsigned a = 0, b = 0, c = 0, d = 0, e = 0, f = 0;
        #pragma unroll
        for (int k = 0; k < 4; ++k) {
            const int sh = k * 8;
            a |= (unsigned)(hr[q * 4 + k] & 255) << sh;
            b |= (unsigned)(lr[q * 4 + k] & 255) << sh;
            c |= (unsigned)(hi[q * 4 + k] & 255) << sh;
            d |= (unsigned)(li[q * 4 + k] & 255) << sh;
            e |= (unsigned)((-hi[q * 4 + k]) & 255) << sh;
            f |= (unsigned)((-li[q * 4 + k]) & 255) << sh;
        }
        dst[0][q] = a; dst[1][q] = b; dst[2][q] = c; dst[3][q] = d; dst[4][q] = e; dst[5][q] = f;
    }
    const size_t b1 = (size_t)row * 2048 + lane * 16;
    *(uint4*)&Wh[b1] = phr;          *(uint4*)&Wl[b1] = plr;
    *(uint4*)&Wh[b1 + 1024] = phi;   *(uint4*)&Wl[b1 + 1024] = pli;
    const size_t b2 = (size_t)row * 1024 + lane * 16;
    *(uint4*)&N2h[b2] = pnh;         *(uint4*)&N2l[b2] = pnl;
}

// ---------------------------------------------------------------------------
// Fused Hermitian GEMM in i8 (verified r6). r10: stores LOWER TRIANGLE only;
// mirror kept only inside diagonal 64-tiles (pA reads those whole).
// ---------------------------------------------------------------------------
__global__ __launch_bounds__(256, 2) void gemm_rho_i8(const char* __restrict__ Wh,
                                                      const char* __restrict__ Wl,
                                                      const char* __restrict__ N2h,
                                                      const char* __restrict__ N2l,
                                                      float2* __restrict__ rho)
{
    __shared__ __align__(16) char sA1h[64 * 64];
    __shared__ __align__(16) char sA1l[64 * 64];
    __shared__ __align__(16) char sA2h[64 * 64];
    __shared__ __align__(16) char sA2l[64 * 64];
    __shared__ __align__(16) char sB1h[128 * 64];
    __shared__ __align__(16) char sB1l[128 * 64];
    __shared__ __align__(16) char sB2h[128 * 64];
    __shared__ __align__(16) char sB2l[128 * 64];
    __shared__ __align__(16) char sN2h[128 * 64];
    __shared__ __align__(16) char sN2l[128 * 64];

    const int b = blockIdx.x;
    int bj = (int)((65.0f - sqrtf(4225.0f - 4.0f * (float)b)) * 0.5f);
    while (bj > 0 && bj * (65 - bj) > b) --bj;
    while ((bj + 1) * (64 - bj) <= b) ++bj;
    const int bi = 2 * bj + (b - bj * (65 - bj));
    const int row0 = bi << 6, col0 = bj << 7;
    const bool full = (bi >= 2 * bj + 2);

    const int t = threadIdx.x;
    const int lane = t & 63, w = t >> 6;
    const int wr = w >> 1, wc = w & 1;

    const int rowA = t >> 2;
    const int kcA = (t & 3) ^ ((rowA >> 1) & 3);
    const size_t aoff = (size_t)(row0 + rowA) * 2048 + kcA * 16;
    const int ldsA = t * 16;
    size_t boff[2], boffN[2]; int ldsB[2];
    #pragma unroll
    for (int q = 0; q < 2; ++q) {
        const int g = q * 256 + t;
        const int rowB = g >> 2;
        const int kcB = (g & 3) ^ ((rowB >> 1) & 3);
        boff[q]  = (size_t)(col0 + rowB) * 2048 + kcB * 16;
        boffN[q] = (size_t)(col0 + rowB) * 1024 + kcB * 16;
        ldsB[q] = g * 16;
    }

    const int m = lane & 15, gq = lane >> 4;
    const int fko = (gq ^ ((m >> 1) & 3)) * 16;

    i32x4 rehh[2][4], remx[2][4], imhh[2][4], immx[2][4];
    #pragma unroll
    for (int i = 0; i < 2; ++i)
        #pragma unroll
        for (int j = 0; j < 4; ++j) {
            rehh[i][j] = (i32x4){0, 0, 0, 0}; remx[i][j] = (i32x4){0, 0, 0, 0};
            imhh[i][j] = (i32x4){0, 0, 0, 0}; immx[i][j] = (i32x4){0, 0, 0, 0};
        }

    for (int kt = 0; kt < RANK; kt += 64) {
        load_lds16(Wh + aoff + kt,        &sA1h[ldsA]);
        load_lds16(Wl + aoff + kt,        &sA1l[ldsA]);
        load_lds16(Wh + aoff + kt + 1024, &sA2h[ldsA]);
        load_lds16(Wl + aoff + kt + 1024, &sA2l[ldsA]);
        #pragma unroll
        for (int q = 0; q < 2; ++q) {
            load_lds16(Wh + boff[q] + kt,        &sB1h[ldsB[q]]);
            load_lds16(Wl + boff[q] + kt,        &sB1l[ldsB[q]]);
            load_lds16(Wh + boff[q] + kt + 1024, &sB2h[ldsB[q]]);
            load_lds16(Wl + boff[q] + kt + 1024, &sB2l[ldsB[q]]);
            load_lds16(N2h + boffN[q] + kt,      &sN2h[ldsB[q]]);
            load_lds16(N2l + boffN[q] + kt,      &sN2l[ldsB[q]]);
        }
        __syncthreads();

        i32x4 fa1h[2], fa1l[2], fa2h[2], fa2l[2];
        #pragma unroll
        for (int i = 0; i < 2; ++i) {
            const int off = (wr * 32 + i * 16 + m) * 64 + fko;
            fa1h[i] = *(const i32x4*)&sA1h[off];
            fa1l[i] = *(const i32x4*)&sA1l[off];
            fa2h[i] = *(const i32x4*)&sA2h[off];
            fa2l[i] = *(const i32x4*)&sA2l[off];
        }
        #pragma unroll
        for (int j = 0; j < 4; ++j) {
            const int off = (wc * 64 + j * 16 + m) * 64 + fko;
            const i32x4 b1h = *(const i32x4*)&sB1h[off];
            const i32x4 b1l = *(const i32x4*)&sB1l[off];
            const i32x4 b2h = *(const i32x4*)&sB2h[off];
            const i32x4 b2l = *(const i32x4*)&sB2l[off];
            const i32x4 n2h = *(const i32x4*)&sN2h[off];
            const i32x4 n2l = *(const i32x4*)&sN2l[off];
            #pragma unroll
            for (int i = 0; i < 2; ++i) {
                i32x4 r = rehh[i][j];
                r = __builtin_amdgcn_mfma_i32_16x16x64_i8(fa1h[i], b1h, r, 0, 0, 0);
                r = __builtin_amdgcn_mfma_i32_16x16x64_i8(fa2h[i], b2h, r, 0, 0, 0);
                rehh[i][j] = r;
                r = remx[i][j];
                r = __builtin_amdgcn_mfma_i32_16x16x64_i8(fa1h[i], b1l, r, 0, 0, 0);
                r = __builtin_amdgcn_mfma_i32_16x16x64_i8(fa1l[i], b1h, r, 0, 0, 0);
                r = __builtin_amdgcn_mfma_i32_16x16x64_i8(fa2h[i], b2l, r, 0, 0, 0);
                r = __builtin_amdgcn_mfma_i32_16x16x64_i8(fa2l[i], b2h, r, 0, 0, 0);
                remx[i][j] = r;
                r = imhh[i][j];
                r = __builtin_amdgcn_mfma_i32_16x16x64_i8(fa2h[i], b1h, r, 0, 0, 0);
                r = __builtin_amdgcn_mfma_i32_16x16x64_i8(fa1h[i], n2h, r, 0, 0, 0);
                imhh[i][j] = r;
                r = immx[i][j];
                r = __builtin_amdgcn_mfma_i32_16x16x64_i8(fa2h[i], b1l, r, 0, 0, 0);
                r = __builtin_amdgcn_mfma_i32_16x16x64_i8(fa2l[i], b1h, r, 0, 0, 0);
                r = __builtin_amdgcn_mfma_i32_16x16x64_i8(fa1h[i], n2l, r, 0, 0, 0);
                r = __builtin_amdgcn_mfma_i32_16x16x64_i8(fa1l[i], n2h, r, 0, 0, 0);
                immx[i][j] = r;
            }
        }
        __syncthreads();
    }

    #pragma unroll
    for (int i = 0; i < 2; ++i)
        #pragma unroll
        for (int j = 0; j < 4; ++j) {
            const int col = col0 + wc * 64 + j * 16 + m;
            const float sc = g_scale[col];
            #pragma unroll
            for (int r = 0; r < 4; ++r) {
                const int row = row0 + wr * 32 + i * 16 + gq * 4 + r;
                const float s2 = g_scale[row] * sc;
                const float re = s2 * (16384.f * (float)rehh[i][j][r] + 128.f * (float)remx[i][j][r]);
                const float im = s2 * (16384.f * (float)imhh[i][j][r] + 128.f * (float)immx[i][j][r]);
                if (full || row >= col) rho[(size_t)row * D + col] = make_float2(re, im);
                // mirror only inside diagonal 64-tiles (pA reads those whole)
                if (row > col && ((row >> 6) == (col >> 6)))
                    rho[(size_t)col * D + row] = make_float2(re, -im);
            }
        }
}

// ---------------------------------------------------------------------------
__global__ void trace_inv(const float2* __restrict__ rho)
{
    __shared__ float red[256];
    float s = 0.f;
    for (int d = threadIdx.x; d < D; d += 256)
        s += rho[(size_t)d * (D + 1)].x;
    red[threadIdx.x] = s;
    __syncthreads();
    for (int off = 128; off > 0; off >>= 1) {
        if (threadIdx.x < off) red[threadIdx.x] += red[threadIdx.x + off];
        __syncthreads();
    }
    if (threadIdx.x == 0) g_inv_tr[0] = 1.0f / red[0];
}

// ---------------------------------------------------------------------------
// 2-qubit staged contraction on a 4x4 register tile (verified r9).
// ---------------------------------------------------------------------------
static __device__ __forceinline__ void qmt2(float2* x,
                                            const float* __restrict__ Mre,
                                            const float* __restrict__ Mim)
{
    float2 y[16];
    #pragma unroll
    for (int sb = 0; sb < 4; ++sb)
        #pragma unroll
        for (int ja = 0; ja < 2; ++ja)
            #pragma unroll
            for (int ia = 0; ia < 2; ++ia) {
                float2 acc = make_float2(0.f, 0.f);
                #pragma unroll
                for (int ib = 0; ib < 2; ++ib)
                    #pragma unroll
                    for (int jb = 0; jb < 2; ++jb) {
                        const float mr = Mre[sb * 4 + ib * 2 + jb];
                        const float mi = Mim[sb * 4 + ib * 2 + jb];
                        const float2 v = x[(ja * 2 + jb) * 4 + ia * 2 + ib];
                        acc.x += mr * v.x - mi * v.y;
                        acc.y += mr * v.y + mi * v.x;
                    }
                y[sb * 4 + ja * 2 + ia] = acc;
            }
    #pragma unroll
    for (int sa = 0; sa < 4; ++sa)
        #pragma unroll
        for (int sb = 0; sb < 4; ++sb) {
            float2 acc = make_float2(0.f, 0.f);
            #pragma unroll
            for (int ia = 0; ia < 2; ++ia)
                #pragma unroll
                for (int ja = 0; ja < 2; ++ja) {
                    const float mr = Mre[sa * 4 + ia * 2 + ja];
                    const float mi = Mim[sa * 4 + ia * 2 + ja];
                    const float2 v = y[sb * 4 + ja * 2 + ia];
                    acc.x += mr * v.x - mi * v.y;
                    acc.y += mr * v.y + mi * v.x;
                }
            x[sa * 4 + sb] = acc;
        }
}

// ---------------------------------------------------------------------------
// The r9 3-stage pipeline (2 LDS exchanges), factored. Mutates x[16] from
// stage-1 input tile to the 16 final d3-values for slot (e2,e1)=(t>>4,t&15).
// No trailing barrier: caller must sync before reusing X.
// ---------------------------------------------------------------------------
static __device__ __forceinline__ void pA_pipeline(float2* x, float2* X, const int t,
                                                   const float* __restrict__ mre,
                                                   const float* __restrict__ mim)
{
    qmt2(x, mre, mim);
    #pragma unroll
    for (int d = 0; d < 16; ++d) X[t * 17 + d] = x[d];
    __syncthreads();
    const int a2 = t >> 6, t2 = (t >> 4) & 3, d1 = t & 15;
    #pragma unroll
    for (int j2 = 0; j2 < 4; ++j2)
        #pragma unroll
        for (int i2 = 0; i2 < 4; ++i2)
            x[j2 * 4 + i2] = X[((a2 * 4 + j2) * 16 + t2 * 4 + i2) * 17 + d1];
    __syncthreads();
    qmt2(x, mre, mim);
    #pragma unroll
    for (int d = 0; d < 16; ++d) X[(a2 * 4 + t2) * 257 + d * 16 + d1] = x[d];
    __syncthreads();
    const int e2 = t >> 4, e1 = t & 15;
    #pragma unroll
    for (int j2 = 0; j2 < 4; ++j2)
        #pragma unroll
        for (int i2 = 0; i2 < 4; ++i2)
            x[j2 * 4 + i2] = X[(j2 * 4 + i2) * 257 + e2 * 16 + e1];
    qmt2(x, mre, mim);
}

// ---------------------------------------------------------------------------
// Fused pass A, Hermitian version (r10): only lower-triangle tiles (rr>=cc),
// 2080 groups. Off-diagonal tiles run the pipeline twice on the SAME read:
//   out(rr,cc) = qmt_M(T);  out(cc,rr) = conj(qmt_{M†}(T))
// (identity: qmt_M(conj(T^T)) = conj(qmt_{M†}(T)); M† tables precomputed).
// Output layout identical to r9: [rr, cc, d3 d2 d1].
// ---------------------------------------------------------------------------
__global__ __launch_bounds__(256) void qmt_pAh(const float2* __restrict__ in,
                                               float2* __restrict__ out,
                                               const float* __restrict__ Mre,
                                               const float* __restrict__ Mim)
{
    __shared__ __align__(16) float2 X[256 * 17];   // 34816 B
    const int t = threadIdx.x;
    const int g = blockIdx.x;                      // 2080 triangle groups
    int rr = (int)((sqrtf(8.f * (float)g + 1.f) - 1.f) * 0.5f);
    while (rr * (rr + 1) / 2 > g) --rr;
    while ((rr + 1) * (rr + 2) / 2 <= g) ++rr;
    const int cc = g - rr * (rr + 1) / 2;          // cc <= rr

    const int a4 = t >> 4, t4 = t & 15;
    float2 x0[16], x[16];
    #pragma unroll
    for (int j2 = 0; j2 < 4; ++j2) {
        const float2* p = in + ((size_t)(rr * 64 + a4 * 4 + j2)) * 4096 + cc * 64 + t4 * 4;
        const float4 v0 = ((const float4*)p)[0];
        const float4 v1 = ((const float4*)p)[1];
        x0[j2 * 4 + 0] = make_float2(v0.x, v0.y);
        x0[j2 * 4 + 1] = make_float2(v0.z, v0.w);
        x0[j2 * 4 + 2] = make_float2(v1.x, v1.y);
        x0[j2 * 4 + 3] = make_float2(v1.z, v1.w);
    }

    // pass 0: M, output group (rr,cc)
    #pragma unroll
    for (int q = 0; q < 16; ++q) x[q] = x0[q];
    pA_pipeline(x, X, t, Mre, Mim);
    const int e2 = t >> 4, e1 = t & 15;
    const size_t ob0 = (size_t)(rr * 64 + cc) * 4096 + e2 * 16 + e1;
    #pragma unroll
    for (int d = 0; d < 16; ++d) out[ob0 + (size_t)d * 256] = x[d];

    // pass 1: M-dagger + conjugate, output group (cc,rr)
    if (rr != cc) {
        __syncthreads();   // pass-0 stage-3 reads of X complete
        #pragma unroll
        for (int q = 0; q < 16; ++q) x[q] = x0[q];
        pA_pipeline(x, X, t, g_mdre, g_mdim);
        const size_t ob1 = (size_t)(cc * 64 + rr) * 4096 + e2 * 16 + e1;
        #pragma unroll
        for (int d = 0; d < 16; ++d)
            out[ob1 + (size_t)d * 256] = make_float2(x[d].x, -x[d].y);
    }
}

// ---------------------------------------------------------------------------
// Staged 3-qubit contraction (verified r4-r9) — used by p3/p4.
// ---------------------------------------------------------------------------
static __device__ __forceinline__ void qmt_stage_cb(float2* x,
                                                    const float* __restrict__ Mre,
                                                    const float* __restrict__ Mim)
{
    #pragma unroll
    for (int jj = 0; jj < 4; ++jj) {
        float2 y[16];
        #pragma unroll
        for (int sc = 0; sc < 4; ++sc)
            #pragma unroll
            for (int ii = 0; ii < 4; ++ii) {
                float2 acc = make_float2(0.f, 0.f);
                #pragma unroll
                for (int ic = 0; ic < 2; ++ic)
                    #pragma unroll
                    for (int jc = 0; jc < 2; ++jc) {
                        const float mr = Mre[sc * 4 + ic * 2 + jc];
                        const float mi = Mim[sc * 4 + ic * 2 + jc];
                        const float2 v = x[jj * 16 + jc * 8 + ii * 2 + ic];
                        acc.x += mr * v.x - mi * v.y;
                        acc.y += mr * v.y + mi * v.x;
                    }
                y[sc * 4 + ii] = acc;
            }
        #pragma unroll
        for (int q = 0; q < 16; ++q) x[jj * 16 + q] = y[q];
    }

    #pragma unroll
    for (int ja = 0; ja < 2; ++ja)
        #pragma unroll
        for (int sc = 0; sc < 4; ++sc) {
            float2 z[8];
            #pragma unroll
            for (int sb = 0; sb < 4; ++sb)
                #pragma unroll
                for (int ia = 0; ia < 2; ++ia) {
                    float2 acc = make_float2(0.f, 0.f);
                    #pragma unroll
                    for (int ib = 0; ib < 2; ++ib)
                        #pragma unroll
                        for (int jb = 0; jb < 2; ++jb) {
                            const float mr = Mre[sb * 4 + ib * 2 + jb];
                            const float mi = Mim[sb * 4 + ib * 2 + jb];
                            const float2 v = x[(ja * 2 + jb) * 16 + sc * 4 + ia * 2 + ib];
                            acc.x += mr * v.x - mi * v.y;
                            acc.y += mr * v.y + mi * v.x;
                        }
                    z[sb * 2 + ia] = acc;
                }
            #pragma unroll
            for (int sb = 0; sb < 4; ++sb)
                #pragma unroll
                for (int ia = 0; ia < 2; ++ia)
                    x[ja * 32 + (sb >> 1) * 16 + sc * 4 + ia * 2 + (sb & 1)] = z[sb * 2 + ia];
        }
}

#define QMT_STAGE_A(STORE)                                                     \
    _Pragma("unroll")                                                          \
    for (int sbH = 0; sbH < 2; ++sbH)                                          \
        _Pragma("unroll")                                                      \
        for (int sc = 0; sc < 4; ++sc)                                         \
            _Pragma("unroll")                                                  \
            for (int sbL = 0; sbL < 2; ++sbL) {                                \
                const int sb = sbH * 2 + sbL;                                  \
                _Pragma("unroll")                                              \
                for (int sa = 0; sa < 4; ++sa) {                               \
                    float2 acc = make_float2(0.f, 0.f);                        \
                    _Pragma("unroll")                                          \
                    for (int ia = 0; ia < 2; ++ia)                             \
                        _Pragma("unroll")                                      \
                        for (int ja = 0; ja < 2; ++ja) {                       \
                            const float mr = Mre[sa * 4 + ia * 2 + ja];        \
                            const float mi = Mim[sa * 4 + ia * 2 + ja];        \
                            const float2 v = x[ja * 32 + sbH * 16 + sc * 4 + ia * 2 + sbL]; \
                            acc.x += mr * v.x - mi * v.y;                      \
                            acc.y += mr * v.y + mi * v.x;                      \
                        }                                                      \
                    const int s3 = sa * 16 + sb * 4 + sc;                      \
                    STORE;                                                     \
                }                                                              \
            }

// ---------------------------------------------------------------------------
// Pass B (= p3): in [rr(64), cc(64), S(4096)]; out [r3,c3, s3(64), S].
// ---------------------------------------------------------------------------
__global__ __launch_bounds__(256) void qmt_p3(const float2* __restrict__ in,
                                              float2* __restrict__ out,
                                              const float* __restrict__ Mre,
                                              const float* __restrict__ Mim)
{
    const int tid = blockIdx.x * 256 + threadIdx.x;
    const int s = tid & 4095, c3 = (tid >> 12) & 7, r3 = tid >> 15;

    float2 x[64];
    #pragma unroll
    for (int j3 = 0; j3 < 8; ++j3)
        #pragma unroll
        for (int i3 = 0; i3 < 8; ++i3)
            x[j3 * 8 + i3] = in[(size_t)((r3 * 8 + j3) * 64 + c3 * 8 + i3) * 4096 + s];
    qmt_stage_cb(x, Mre, Mim);
    const size_t ob = ((size_t)(r3 * 8 + c3) * 64) * 4096 + s;
    QMT_STAGE_A(out[ob + s3 * 4096] = acc)
}

// ---------------------------------------------------------------------------
// Pass C (= p4, MSB triplet): real-only out [s_hi, s3(64), s_lo(32)].
// ---------------------------------------------------------------------------
__global__ __launch_bounds__(256) void qmt_p4(const float2* __restrict__ in,
                                              float* __restrict__ out,
                                              const float* __restrict__ Mre,
                                              const float* __restrict__ Mim)
{
    const int tid = blockIdx.x * 256 + threadIdx.x;   // 2^18
    float2 x[64];
    #pragma unroll
    for (int j3 = 0; j3 < 8; ++j3)
        #pragma unroll
        for (int i3 = 0; i3 < 8; ++i3)
            x[j3 * 8 + i3] = in[(size_t)(j3 * 8 + i3) * 262144 + tid];
    qmt_stage_cb(x, Mre, Mim);
    const size_t ob = (size_t)(tid >> 5) * 2048 + (tid & 31);
    QMT_STAGE_A(out[ob + s3 * 32] = acc.x)
}

// ---------------------------------------------------------------------------
__global__ void gather_idx(const float* __restrict__ P, const int* __restrict__ idxs,
                           float* __restrict__ out, const int n)
{
    const int i = blockIdx.x * 256 + threadIdx.x;
    if (i < n) {
        const int idx = idxs[i];
        const int s = idx & 262143;
        const size_t pos = (size_t)(s >> 5) * 2048 + (size_t)(idx >> 18) * 32 + (s & 31);
        out[i] = P[pos] * g_inv_tr[0];
    }
}

// ---------------------------------------------------------------------------
extern "C" void kernel_launch(void* const* d_in, const int* in_sizes, int n_in,
                              void* d_out, int out_size, void* d_ws, size_t ws_size,
                              hipStream_t stream)
{
    const float* params = (const float*)d_in[0];  // (2, D, RANK) fp32
    const float* Mre    = (const float*)d_in[1];
    const float* Mim    = (const float*)d_in[2];
    const int*   idxs   = (const int*)d_in[3];
    float*       out    = (float*)d_out;

    float* ws = (float*)d_ws;
    float2* A  = (float2*)ws;                 // 134 MB plane
    float2* Bp = (float2*)(ws + 2 * NTOT);    // 134 MB plane
    // i8 planes in the (dead until pass A) B region: 25 MB
    char* Wh  = (char*)Bp;
    char* Wl  = Wh + (size_t)D * 2048;
    char* N2h = Wl + (size_t)D * 2048;
    char* N2l = N2h + (size_t)D * 1024;

    convert_w_i8<<<1024, 256, 0, stream>>>(params, Mre, Mim, Wh, Wl, N2h, N2l);
    gemm_rho_i8<<<1056, 256, 0, stream>>>(Wh, Wl, N2h, N2l, A);
    trace_inv<<<1, 256, 0, stream>>>(A);

    qmt_pAh<<<2080, 256, 0, stream>>>(A, Bp, Mre, Mim);  // 6 LSB qubits, triangle
    qmt_p3<<<1024, 256, 0, stream>>>(Bp, A, Mre, Mim);   // 3 qubits
    qmt_p4<<<1024, 256, 0, stream>>>(A, (float*)Bp, Mre, Mim);  // 3 qubits, real out

    gather_idx<<<(out_size + 255) / 256, 256, 0, stream>>>((float*)Bp, idxs, out, out_size);
}